// Round 2
// baseline (761.226 us; speedup 1.0000x reference)
//
#include <hip/hip_runtime.h>

typedef unsigned short u16;
typedef __attribute__((ext_vector_type(8))) short short8;
typedef __attribute__((ext_vector_type(4))) float f32x4;
typedef __attribute__((ext_vector_type(4))) u16 u16x4;
typedef __attribute__((ext_vector_type(4))) unsigned int u32x4;

#define DEVINL static __device__ __forceinline__

DEVINL u16 f2bf(float f) {
  unsigned u = __builtin_bit_cast(unsigned, f);
  u += 0x7fffu + ((u >> 16) & 1u);
  return (u16)(u >> 16);
}
DEVINL float bf2f(u16 h) {
  return __builtin_bit_cast(float, ((unsigned)h) << 16);
}

// async global->LDS, 16B per lane; lds base must be wave-uniform
DEVINL void gload16(const void* g, void* l) {
  __builtin_amdgcn_global_load_lds(
      (const __attribute__((address_space(1))) void*)g,
      (__attribute__((address_space(3))) void*)l, 16, 0, 0);
}

// ---------------- converts ----------------

// hidden [S=1024, B=32, H=1024] f32 -> hhi/hlo [B, S, H] split bf16
__global__ __launch_bounds__(256) void cvt_hidden_split_k(const float* __restrict__ hid,
                                                          u16* __restrict__ hhi,
                                                          u16* __restrict__ hlo) {
  const int s = blockIdx.x;  // 0..1023
  const int b = blockIdx.y;  // 0..31
  const int t = threadIdx.x;
  const f32x4 v = ((const f32x4*)(hid + ((size_t)s * 32 + b) * 1024))[t];
  u16x4 oh, ol;
#pragma unroll
  for (int j = 0; j < 4; ++j) {
    const u16 hi = f2bf(v[j]);
    oh[j] = hi;
    ol[j] = f2bf(v[j] - bf2f(hi));
  }
  const size_t base = ((size_t)b * 1024 + s) * 1024;
  ((u16x4*)(hhi + base))[t] = oh;
  ((u16x4*)(hlo + base))[t] = ol;
}

// generic f32 -> split bf16 (hi, lo)
__global__ __launch_bounds__(256) void cvt_split_k(const float* __restrict__ in,
                                                   u16* __restrict__ hi_o,
                                                   u16* __restrict__ lo_o, long n4) {
  long i = (long)blockIdx.x * 256 + threadIdx.x;
  const long stride = (long)gridDim.x * 256;
  for (; i < n4; i += stride) {
    const f32x4 v = ((const f32x4*)in)[i];
    u16x4 oh, ol;
#pragma unroll
    for (int j = 0; j < 4; ++j) {
      const u16 hi = f2bf(v[j]);
      oh[j] = hi;
      ol[j] = f2bf(v[j] - bf2f(hi));
    }
    ((u16x4*)hi_o)[i] = oh;
    ((u16x4*)lo_o)[i] = ol;
  }
}

// generic f32 -> bf16 (single)
__global__ __launch_bounds__(256) void cvt_f32_bf16_k(const float* __restrict__ in,
                                                      u16* __restrict__ out, long n4) {
  long i = (long)blockIdx.x * 256 + threadIdx.x;
  const long stride = (long)gridDim.x * 256;
  for (; i < n4; i += stride) {
    const f32x4 v = ((const f32x4*)in)[i];
    u16x4 o;
#pragma unroll
    for (int j = 0; j < 4; ++j) o[j] = f2bf(v[j]);
    ((u16x4*)out)[i] = o;
  }
}

// ---------------- single-precision GEMM: C = A * Bt^T + bias, bf16 out ----------------
// 128x128 tile, BK=32, 4 waves, each wave 64x64 as 4x4 of 16x16x32 MFMA fragments.
__global__ __launch_bounds__(256) void gemm_bt_k(
    const u16* __restrict__ A, const u16* __restrict__ Bt,
    const float* __restrict__ bias, u16* __restrict__ C,
    int lda, int ldb, int ldc, int nk) {
  __shared__ u16 As[128 * 32];
  __shared__ u16 Bs[128 * 32];
  const int tid = threadIdx.x;
  const int lane = tid & 63, wid = tid >> 6;
  const int wr = wid >> 1, wc = wid & 1;
  const int m0 = blockIdx.x * 128;
  const int n0 = blockIdx.y * 128;

  f32x4 acc[4][4] = {};
  const int r_in = lane >> 2;
  const int c8 = (lane & 3) * 8;

  for (int kt = 0; kt < nk; ++kt) {
    const int k0 = kt * 32;
    __syncthreads();
#pragma unroll
    for (int i = 0; i < 2; ++i) {
      const int ch = wid + i * 4;
      const int row = ch * 16 + r_in;
      gload16(A + (size_t)(m0 + row) * lda + k0 + c8, &As[ch * 512]);
      gload16(Bt + (size_t)(n0 + row) * ldb + k0 + c8, &Bs[ch * 512]);
    }
    __syncthreads();
    short8 af[4], bfr[4];
#pragma unroll
    for (int m = 0; m < 4; ++m)
      af[m] = *(const short8*)&As[(wr * 64 + m * 16 + (lane & 15)) * 32 + (lane >> 4) * 8];
#pragma unroll
    for (int n = 0; n < 4; ++n)
      bfr[n] = *(const short8*)&Bs[(wc * 64 + n * 16 + (lane & 15)) * 32 + (lane >> 4) * 8];
#pragma unroll
    for (int m = 0; m < 4; ++m)
#pragma unroll
      for (int n = 0; n < 4; ++n)
        acc[m][n] = __builtin_amdgcn_mfma_f32_16x16x32_bf16(af[m], bfr[n], acc[m][n], 0, 0, 0);
  }

  const int cb = n0 + wc * 64 + (lane & 15);
  const int rb = m0 + wr * 64 + (lane >> 4) * 4;
#pragma unroll
  for (int n = 0; n < 4; ++n) {
    const int col = cb + n * 16;
    const float bv = bias[col];
#pragma unroll
    for (int m = 0; m < 4; ++m) {
      const int row = rb + m * 16;
#pragma unroll
      for (int j = 0; j < 4; ++j)
        C[(size_t)(row + j) * ldc + col] = f2bf(acc[m][n][j] + bv);
    }
  }
}

// ---------------- split-precision 3-pass GEMM: C = (Ah+Al)*(Bh+Bl)^T (+bias) ----------------
// acc = Ah*Bh + Ah*Bl + Al*Bh  (lo*lo dropped, ~2^-18 relative)
// MODE 0: split bf16 out (Chi, Clo) + f32 bias.  MODE 1: f32 out (C0), no bias.
template <int MODE>
__global__ __launch_bounds__(256) void gemm3_bt_k(
    const u16* __restrict__ Ah, const u16* __restrict__ Al,
    const u16* __restrict__ Bh, const u16* __restrict__ Bl,
    const float* __restrict__ bias,
    void* __restrict__ C0, void* __restrict__ C1,
    int lda, int ldb, int ldc, int nk, long sA, long sB, long sC) {
  __shared__ u16 Ash[128 * 32];
  __shared__ u16 Asl[128 * 32];
  __shared__ u16 Bsh[128 * 32];
  __shared__ u16 Bsl[128 * 32];
  const int tid = threadIdx.x;
  const int lane = tid & 63, wid = tid >> 6;
  const int wr = wid >> 1, wc = wid & 1;
  const int z = blockIdx.z;
  Ah += (size_t)z * sA; Al += (size_t)z * sA;
  Bh += (size_t)z * sB; Bl += (size_t)z * sB;
  const int m0 = blockIdx.x * 128;
  const int n0 = blockIdx.y * 128;

  f32x4 acc[4][4] = {};
  const int r_in = lane >> 2;
  const int c8 = (lane & 3) * 8;

  for (int kt = 0; kt < nk; ++kt) {
    const int k0 = kt * 32;
    __syncthreads();
#pragma unroll
    for (int i = 0; i < 2; ++i) {
      const int ch = wid + i * 4;
      const int row = ch * 16 + r_in;
      const size_t ga = (size_t)(m0 + row) * lda + k0 + c8;
      const size_t gb = (size_t)(n0 + row) * ldb + k0 + c8;
      gload16(Ah + ga, &Ash[ch * 512]);
      gload16(Al + ga, &Asl[ch * 512]);
      gload16(Bh + gb, &Bsh[ch * 512]);
      gload16(Bl + gb, &Bsl[ch * 512]);
    }
    __syncthreads();
    short8 ah[4], al[4], bh[4], bl[4];
#pragma unroll
    for (int m = 0; m < 4; ++m) {
      const int off = (wr * 64 + m * 16 + (lane & 15)) * 32 + (lane >> 4) * 8;
      ah[m] = *(const short8*)&Ash[off];
      al[m] = *(const short8*)&Asl[off];
    }
#pragma unroll
    for (int n = 0; n < 4; ++n) {
      const int off = (wc * 64 + n * 16 + (lane & 15)) * 32 + (lane >> 4) * 8;
      bh[n] = *(const short8*)&Bsh[off];
      bl[n] = *(const short8*)&Bsl[off];
    }
#pragma unroll
    for (int m = 0; m < 4; ++m)
#pragma unroll
      for (int n = 0; n < 4; ++n) {
        acc[m][n] = __builtin_amdgcn_mfma_f32_16x16x32_bf16(ah[m], bh[n], acc[m][n], 0, 0, 0);
        acc[m][n] = __builtin_amdgcn_mfma_f32_16x16x32_bf16(ah[m], bl[n], acc[m][n], 0, 0, 0);
        acc[m][n] = __builtin_amdgcn_mfma_f32_16x16x32_bf16(al[m], bh[n], acc[m][n], 0, 0, 0);
      }
  }

  const int cb = n0 + wc * 64 + (lane & 15);
  const int rb = m0 + wr * 64 + (lane >> 4) * 4;
  if (MODE == 0) {
    u16* Chi = (u16*)C0;
    u16* Clo = (u16*)C1;
#pragma unroll
    for (int n = 0; n < 4; ++n) {
      const int col = cb + n * 16;
      const float bv = bias[col];
#pragma unroll
      for (int m = 0; m < 4; ++m) {
        const int row = rb + m * 16;
#pragma unroll
        for (int j = 0; j < 4; ++j) {
          const float kv = acc[m][n][j] + bv;
          const u16 hi = f2bf(kv);
          Chi[(size_t)(row + j) * ldc + col] = hi;
          Clo[(size_t)(row + j) * ldc + col] = f2bf(kv - bf2f(hi));
        }
      }
    }
  } else {
    float* C = (float*)C0 + (size_t)z * sC;
#pragma unroll
    for (int n = 0; n < 4; ++n) {
      const int col = cb + n * 16;
#pragma unroll
      for (int m = 0; m < 4; ++m) {
        const int row = rb + m * 16;
#pragma unroll
        for (int j = 0; j < 4; ++j)
          C[(size_t)(row + j) * ldc + col] = acc[m][n][j];
      }
    }
  }
}

// ---------------- softmax over last dim (1024), in-place bf16 write ----------------
__global__ __launch_bounds__(256) void softmax_k(float* __restrict__ S) {
  float* rp = S + (size_t)blockIdx.x * 1024;
  const int tid = threadIdx.x;
  const int lane = tid & 63, wid = tid >> 6;
  const f32x4 v = ((const f32x4*)rp)[tid];
  float mx = fmaxf(fmaxf(v[0], v[1]), fmaxf(v[2], v[3]));
#pragma unroll
  for (int off = 32; off; off >>= 1) mx = fmaxf(mx, __shfl_xor(mx, off));
  __shared__ float red[4];
  __shared__ float red2[4];
  if (lane == 0) red[wid] = mx;
  __syncthreads();
  mx = fmaxf(fmaxf(red[0], red[1]), fmaxf(red[2], red[3]));
  const float e0 = __expf(v[0] - mx), e1 = __expf(v[1] - mx);
  const float e2 = __expf(v[2] - mx), e3 = __expf(v[3] - mx);
  float s = (e0 + e1) + (e2 + e3);
#pragma unroll
  for (int off = 32; off; off >>= 1) s += __shfl_xor(s, off);
  if (lane == 0) red2[wid] = s;
  __syncthreads();
  const float inv = 1.0f / (red2[0] + red2[1] + red2[2] + red2[3]);
  u16x4 o;
  o[0] = f2bf(e0 * inv); o[1] = f2bf(e1 * inv); o[2] = f2bf(e2 * inv); o[3] = f2bf(e3 * inv);
  ((u16x4*)rp)[tid] = o;  // bytes [0,2048) of this row's own 4096B span: race-free
}

// ---------------- PV: out = sigmoid(attn * V), V row-major [s][h] (transposed staging) ----------------
__global__ __launch_bounds__(256) void gemm_pv_k(
    const u16* __restrict__ Attn, const u16* __restrict__ V,
    float* __restrict__ Out, int lda, int ldb, int ldc, int nk,
    long sA, long sB, long sC) {
  __shared__ u16 As[128 * 32];
  __shared__ u16 Bs[128 * 40];  // [h 128][s 32] pitch 40
  const int tid = threadIdx.x;
  const int lane = tid & 63, wid = tid >> 6;
  const int wr = wid >> 1, wc = wid & 1;
  const int z = blockIdx.z;
  Attn += (size_t)z * sA;
  V += (size_t)z * sB;
  const int m0 = blockIdx.x * 128;
  const int n0 = blockIdx.y * 128;

  f32x4 acc[4][4] = {};
  const int r_in = lane >> 2;
  const int c8 = (lane & 3) * 8;

  for (int kt = 0; kt < nk; ++kt) {
    const int k0 = kt * 32;
    __syncthreads();
#pragma unroll
    for (int i = 0; i < 2; ++i) {
      const int ch = wid + i * 4;
      const int row = ch * 16 + r_in;
      gload16(Attn + (size_t)(m0 + row) * lda + k0 + c8, &As[ch * 512]);
    }
#pragma unroll
    for (int i = 0; i < 2; ++i) {
      const int s = i * 16 + (tid >> 4);
      const int h0 = (tid & 15) * 8;
      union { u32x4 v; u16 u[8]; } r;
      r.v = *(const u32x4*)(V + (size_t)(k0 + s) * ldb + n0 + h0);
#pragma unroll
      for (int j = 0; j < 8; ++j) Bs[(h0 + j) * 40 + s] = r.u[j];
    }
    __syncthreads();
    short8 af[4], bfr[4];
#pragma unroll
    for (int m = 0; m < 4; ++m)
      af[m] = *(const short8*)&As[(wr * 64 + m * 16 + (lane & 15)) * 32 + (lane >> 4) * 8];
#pragma unroll
    for (int n = 0; n < 4; ++n)
      bfr[n] = *(const short8*)&Bs[(wc * 64 + n * 16 + (lane & 15)) * 40 + (lane >> 4) * 8];
#pragma unroll
    for (int m = 0; m < 4; ++m)
#pragma unroll
      for (int n = 0; n < 4; ++n)
        acc[m][n] = __builtin_amdgcn_mfma_f32_16x16x32_bf16(af[m], bfr[n], acc[m][n], 0, 0, 0);
  }

  float* C = Out + (size_t)z * sC;
  const int cb = n0 + wc * 64 + (lane & 15);
  const int rb = m0 + wr * 64 + (lane >> 4) * 4;
#pragma unroll
  for (int n = 0; n < 4; ++n) {
    const int col = cb + n * 16;
#pragma unroll
    for (int m = 0; m < 4; ++m) {
      const int row = rb + m * 16;
#pragma unroll
      for (int j = 0; j < 4; ++j) {
        const float x = acc[m][n][j];
        C[(size_t)(row + j) * ldc + col] = 1.0f / (1.0f + __expf(-x));
      }
    }
  }
}

// ---------------- launch ----------------
// Shapes: S=1024, B=32, H=1024, T=512.
// ws layout (bytes), total 341835776 (~326 MB):
//   hhi @ 0         : 64MB [B,S,H] bf16 hi   -> reused as scores f32 / attn bf16
//   hlo @ 67108864  : 64MB [B,S,H] bf16 lo
//   khi @ 134217728 : 64MB
//   klo @ 201326592 : 64MB
//   v   @ 268435456 : 64MB
//   w   @ 335544320 : kw_hi 2MB | kw_lo 2MB | vw 2MB
// x split bf16 (32MB + 32MB) lives in d_out (64MB f32) until PV overwrites it.
extern "C" void kernel_launch(void* const* d_in, const int* in_sizes, int n_in,
                              void* d_out, int out_size, void* d_ws, size_t ws_size,
                              hipStream_t stream) {
  const float* hidden = (const float*)d_in[0];
  const float* x = (const float*)d_in[1];
  // d_in[2] problem_q unused by the reference
  const float* K_w = (const float*)d_in[3];
  const float* K_b = (const float*)d_in[4];
  const float* V_w = (const float*)d_in[5];
  const float* V_b = (const float*)d_in[6];

  char* ws = (char*)d_ws;
  u16* hhi = (u16*)(ws);
  u16* hlo = (u16*)(ws + 67108864);
  u16* khi = (u16*)(ws + 134217728);
  u16* klo = (u16*)(ws + 201326592);
  u16* vbf = (u16*)(ws + 268435456);
  u16* kwh = (u16*)(ws + 335544320);
  u16* kwl = kwh + 1024 * 1024;
  u16* vw  = kwh + 2 * 1024 * 1024;
  float* scoresF = (float*)hhi;  // reused after projections
  u16* xhi = (u16*)d_out;
  u16* xlo = xhi + 32L * 512 * 1024;
  float* out = (float*)d_out;

  // 1. hidden [S,B,H] -> split bf16 [B,S,H]
  cvt_hidden_split_k<<<dim3(1024, 32), 256, 0, stream>>>(hidden, hhi, hlo);
  // 2. x -> split bf16 (into d_out)
  cvt_split_k<<<2048, 256, 0, stream>>>(x, xhi, xlo, 32L * 512 * 1024 / 4);
  // 3. weights: K_w split, V_w single
  cvt_split_k<<<1024, 256, 0, stream>>>(K_w, kwh, kwl, 1024L * 1024 / 4);
  cvt_f32_bf16_k<<<1024, 256, 0, stream>>>(V_w, vw, 1024L * 1024 / 4);
  // 4. k = (h @ K_w^T + K_b) split-precision, split bf16 out  (M=32768,N=1024,K=1024)
  gemm3_bt_k<0><<<dim3(256, 8, 1), 256, 0, stream>>>(
      hhi, hlo, kwh, kwl, K_b, khi, klo, 1024, 1024, 1024, 32, 0, 0, 0);
  // 5. v = h_hi @ V_w^T + V_b, single bf16
  gemm_bt_k<<<dim3(256, 8, 1), 256, 0, stream>>>(hhi, vw, V_b, vbf, 1024, 1024, 1024, 32);
  // 6. scores[b] = x[b] @ k[b]^T split-precision, f32 out into hhi region (M=512,N=1024,K=1024)
  gemm3_bt_k<1><<<dim3(4, 8, 32), 256, 0, stream>>>(
      xhi, xlo, khi, klo, nullptr, scoresF, nullptr, 1024, 1024, 1024, 32,
      512L * 1024, 1024L * 1024, 512L * 1024);
  // 7. softmax over S, writes bf16 attn in-place (row stride 2048 u16)
  softmax_k<<<16384, 256, 0, stream>>>(scoresF);
  // 8. out[b] = sigmoid(attn[b] @ v[b])
  gemm_pv_k<<<dim3(4, 8, 32), 256, 0, stream>>>(
      (const u16*)scoresF, vbf, out, 2048, 1024, 1024, 32,
      512L * 2048, 1024L * 1024, 512L * 1024);
}

// Round 3
// 570.751 us; speedup vs baseline: 1.3337x; 1.3337x over previous
//
#include <hip/hip_runtime.h>

typedef unsigned short u16;
typedef __attribute__((ext_vector_type(8))) short short8;
typedef __attribute__((ext_vector_type(4))) float f32x4;
typedef __attribute__((ext_vector_type(4))) u16 u16x4;
typedef __attribute__((ext_vector_type(4))) unsigned int u32x4;

#define DEVINL static __device__ __forceinline__

DEVINL u16 f2bf(float f) {
  unsigned u = __builtin_bit_cast(unsigned, f);
  u += 0x7fffu + ((u >> 16) & 1u);
  return (u16)(u >> 16);
}
DEVINL float bf2f(u16 h) {
  return __builtin_bit_cast(float, ((unsigned)h) << 16);
}

// async global->LDS, 16B per lane; lds base must be wave-uniform
DEVINL void gload16(const void* g, void* l) {
  __builtin_amdgcn_global_load_lds(
      (const __attribute__((address_space(1))) void*)g,
      (__attribute__((address_space(3))) void*)l, 16, 0, 0);
}

// ---------------- converts ----------------

// hidden [S=1024, B=32, H=1024] f32 -> hhi/hlo [B, S, H] split bf16
__global__ __launch_bounds__(256) void cvt_hidden_split_k(const float* __restrict__ hid,
                                                          u16* __restrict__ hhi,
                                                          u16* __restrict__ hlo) {
  const int s = blockIdx.x;
  const int b = blockIdx.y;
  const int t = threadIdx.x;
  const f32x4 v = ((const f32x4*)(hid + ((size_t)s * 32 + b) * 1024))[t];
  u16x4 oh, ol;
#pragma unroll
  for (int j = 0; j < 4; ++j) {
    const u16 hi = f2bf(v[j]);
    oh[j] = hi;
    ol[j] = f2bf(v[j] - bf2f(hi));
  }
  const size_t base = ((size_t)b * 1024 + s) * 1024;
  ((u16x4*)(hhi + base))[t] = oh;
  ((u16x4*)(hlo + base))[t] = ol;
}

// generic f32 -> split bf16 (hi, lo)
__global__ __launch_bounds__(256) void cvt_split_k(const float* __restrict__ in,
                                                   u16* __restrict__ hi_o,
                                                   u16* __restrict__ lo_o, long n4) {
  long i = (long)blockIdx.x * 256 + threadIdx.x;
  const long stride = (long)gridDim.x * 256;
  for (; i < n4; i += stride) {
    const f32x4 v = ((const f32x4*)in)[i];
    u16x4 oh, ol;
#pragma unroll
    for (int j = 0; j < 4; ++j) {
      const u16 hi = f2bf(v[j]);
      oh[j] = hi;
      ol[j] = f2bf(v[j] - bf2f(hi));
    }
    ((u16x4*)hi_o)[i] = oh;
    ((u16x4*)lo_o)[i] = ol;
  }
}

// generic f32 -> bf16 (single)
__global__ __launch_bounds__(256) void cvt_f32_bf16_k(const float* __restrict__ in,
                                                      u16* __restrict__ out, long n4) {
  long i = (long)blockIdx.x * 256 + threadIdx.x;
  const long stride = (long)gridDim.x * 256;
  for (; i < n4; i += stride) {
    const f32x4 v = ((const f32x4*)in)[i];
    u16x4 o;
#pragma unroll
    for (int j = 0; j < 4; ++j) o[j] = f2bf(v[j]);
    ((u16x4*)out)[i] = o;
  }
}

// K_w [j=1024][h=1024] f32 -> transposed split bf16: out[h][j]
__global__ __launch_bounds__(256) void cvt_w_split_t_k(const float* __restrict__ in,
                                                       u16* __restrict__ hi_o,
                                                       u16* __restrict__ lo_o) {
  __shared__ float tile[64][65];
  const int bh = blockIdx.x * 64;  // input col block (h)
  const int bj = blockIdx.y * 64;  // input row block (j)
  const int t = threadIdx.x;
  const int r = t >> 4;
  const int c4 = (t & 15) * 4;
#pragma unroll
  for (int it = 0; it < 4; ++it) {
    const int row = it * 16 + r;
    const f32x4 v = *(const f32x4*)(in + (size_t)(bj + row) * 1024 + bh + c4);
#pragma unroll
    for (int j = 0; j < 4; ++j) tile[c4 + j][row] = v[j];
  }
  __syncthreads();
#pragma unroll
  for (int it = 0; it < 4; ++it) {
    const int hrow = it * 16 + r;
    u16x4 oh, ol;
#pragma unroll
    for (int j = 0; j < 4; ++j) {
      const float f = tile[hrow][c4 + j];
      const u16 hv = f2bf(f);
      oh[j] = hv;
      ol[j] = f2bf(f - bf2f(hv));
    }
    *(u16x4*)(hi_o + (size_t)(bh + hrow) * 1024 + bj + c4) = oh;
    *(u16x4*)(lo_o + (size_t)(bh + hrow) * 1024 + bj + c4) = ol;
  }
}

// ---------------- split-precision 3-pass GEMM: C = (Ah+Al)*(Bh+Bl)^T, split bf16 out ----------------
// q' = x @ K_w (via pre-transposed weights). M=16384, N=1024, K=1024. Grid (M/128, 8).
__global__ __launch_bounds__(256) void gemm3_qp_k(
    const u16* __restrict__ Ah, const u16* __restrict__ Al,
    const u16* __restrict__ Bh, const u16* __restrict__ Bl,
    u16* __restrict__ Chi, u16* __restrict__ Clo) {
  __shared__ u16 Ash[128 * 32];
  __shared__ u16 Asl[128 * 32];
  __shared__ u16 Bsh[128 * 32];
  __shared__ u16 Bsl[128 * 32];
  const int tid = threadIdx.x;
  const int lane = tid & 63, wid = tid >> 6;
  const int wr = wid >> 1, wc = wid & 1;
  const int m0 = blockIdx.x * 128;
  const int n0 = blockIdx.y * 128;

  f32x4 acc[4][4] = {};
  const int r_in = lane >> 2;
  const int c8 = (lane & 3) * 8;

  for (int kt = 0; kt < 32; ++kt) {
    const int k0 = kt * 32;
    __syncthreads();
#pragma unroll
    for (int i = 0; i < 2; ++i) {
      const int ch = wid + i * 4;
      const int row = ch * 16 + r_in;
      const size_t ga = (size_t)(m0 + row) * 1024 + k0 + c8;
      const size_t gb = (size_t)(n0 + row) * 1024 + k0 + c8;
      gload16(Ah + ga, &Ash[ch * 512]);
      gload16(Al + ga, &Asl[ch * 512]);
      gload16(Bh + gb, &Bsh[ch * 512]);
      gload16(Bl + gb, &Bsl[ch * 512]);
    }
    __syncthreads();
    short8 ah[4], al[4], bh[4], bl[4];
#pragma unroll
    for (int m = 0; m < 4; ++m) {
      const int off = (wr * 64 + m * 16 + (lane & 15)) * 32 + (lane >> 4) * 8;
      ah[m] = *(const short8*)&Ash[off];
      al[m] = *(const short8*)&Asl[off];
    }
#pragma unroll
    for (int n = 0; n < 4; ++n) {
      const int off = (wc * 64 + n * 16 + (lane & 15)) * 32 + (lane >> 4) * 8;
      bh[n] = *(const short8*)&Bsh[off];
      bl[n] = *(const short8*)&Bsl[off];
    }
#pragma unroll
    for (int m = 0; m < 4; ++m)
#pragma unroll
      for (int n = 0; n < 4; ++n) {
        acc[m][n] = __builtin_amdgcn_mfma_f32_16x16x32_bf16(ah[m], bh[n], acc[m][n], 0, 0, 0);
        acc[m][n] = __builtin_amdgcn_mfma_f32_16x16x32_bf16(ah[m], bl[n], acc[m][n], 0, 0, 0);
        acc[m][n] = __builtin_amdgcn_mfma_f32_16x16x32_bf16(al[m], bh[n], acc[m][n], 0, 0, 0);
      }
  }

  const int cb = n0 + wc * 64 + (lane & 15);
  const int rb = m0 + wr * 64 + (lane >> 4) * 4;
#pragma unroll
  for (int n = 0; n < 4; ++n) {
    const int col = cb + n * 16;
#pragma unroll
    for (int m = 0; m < 4; ++m) {
      const int row = rb + m * 16;
#pragma unroll
      for (int j = 0; j < 4; ++j) {
        const float kv = acc[m][n][j];
        const u16 hi = f2bf(kv);
        Chi[(size_t)(row + j) * 1024 + col] = hi;
        Clo[(size_t)(row + j) * 1024 + col] = f2bf(kv - bf2f(hi));
      }
    }
  }
}

// ---------------- scores[b] = q'[b] @ hidden[b]^T, 3-pass split, f32 out, XCD-swizzled ----------------
// grid 1024 1-D: per-XCD contiguous batches. M=512/batch (4 blocks), N=1024 (8), B=32.
__global__ __launch_bounds__(256) void gemm3_scores_k(
    const u16* __restrict__ Qh, const u16* __restrict__ Ql,
    const u16* __restrict__ Hh, const u16* __restrict__ Hl,
    float* __restrict__ S) {
  const int wg = blockIdx.x;
  const int swz = (wg & 7) * 128 + (wg >> 3);  // bijective, 1024 = 8*128
  const int z = swz >> 5;
  const int n0 = ((swz >> 2) & 7) * 128;
  const int m0 = (swz & 3) * 128;
  const u16* Ah = Qh + (size_t)z * 512 * 1024;
  const u16* Al = Ql + (size_t)z * 512 * 1024;
  const u16* Bh = Hh + (size_t)z * 1024 * 1024;
  const u16* Bl = Hl + (size_t)z * 1024 * 1024;

  __shared__ u16 Ash[128 * 32];
  __shared__ u16 Asl[128 * 32];
  __shared__ u16 Bsh[128 * 32];
  __shared__ u16 Bsl[128 * 32];
  const int tid = threadIdx.x;
  const int lane = tid & 63, wid = tid >> 6;
  const int wr = wid >> 1, wc = wid & 1;

  f32x4 acc[4][4] = {};
  const int r_in = lane >> 2;
  const int c8 = (lane & 3) * 8;

  for (int kt = 0; kt < 32; ++kt) {
    const int k0 = kt * 32;
    __syncthreads();
#pragma unroll
    for (int i = 0; i < 2; ++i) {
      const int ch = wid + i * 4;
      const int row = ch * 16 + r_in;
      const size_t ga = (size_t)(m0 + row) * 1024 + k0 + c8;
      const size_t gb = (size_t)(n0 + row) * 1024 + k0 + c8;
      gload16(Ah + ga, &Ash[ch * 512]);
      gload16(Al + ga, &Asl[ch * 512]);
      gload16(Bh + gb, &Bsh[ch * 512]);
      gload16(Bl + gb, &Bsl[ch * 512]);
    }
    __syncthreads();
    short8 ah[4], al[4], bh[4], bl[4];
#pragma unroll
    for (int m = 0; m < 4; ++m) {
      const int off = (wr * 64 + m * 16 + (lane & 15)) * 32 + (lane >> 4) * 8;
      ah[m] = *(const short8*)&Ash[off];
      al[m] = *(const short8*)&Asl[off];
    }
#pragma unroll
    for (int n = 0; n < 4; ++n) {
      const int off = (wc * 64 + n * 16 + (lane & 15)) * 32 + (lane >> 4) * 8;
      bh[n] = *(const short8*)&Bsh[off];
      bl[n] = *(const short8*)&Bsl[off];
    }
#pragma unroll
    for (int m = 0; m < 4; ++m)
#pragma unroll
      for (int n = 0; n < 4; ++n) {
        acc[m][n] = __builtin_amdgcn_mfma_f32_16x16x32_bf16(ah[m], bh[n], acc[m][n], 0, 0, 0);
        acc[m][n] = __builtin_amdgcn_mfma_f32_16x16x32_bf16(ah[m], bl[n], acc[m][n], 0, 0, 0);
        acc[m][n] = __builtin_amdgcn_mfma_f32_16x16x32_bf16(al[m], bh[n], acc[m][n], 0, 0, 0);
      }
  }

  float* C = S + (size_t)z * 512 * 1024;
  const int cb = n0 + wc * 64 + (lane & 15);
  const int rb = m0 + wr * 64 + (lane >> 4) * 4;
#pragma unroll
  for (int n = 0; n < 4; ++n) {
    const int col = cb + n * 16;
#pragma unroll
    for (int m = 0; m < 4; ++m) {
      const int row = rb + m * 16;
#pragma unroll
      for (int j = 0; j < 4; ++j)
        C[(size_t)(row + j) * 1024 + col] = acc[m][n][j];
    }
  }
}

// ---------------- softmax over last dim (1024), in-place bf16 write ----------------
__global__ __launch_bounds__(256) void softmax_k(float* __restrict__ S) {
  float* rp = S + (size_t)blockIdx.x * 1024;
  const int tid = threadIdx.x;
  const int lane = tid & 63, wid = tid >> 6;
  const f32x4 v = ((const f32x4*)rp)[tid];
  float mx = fmaxf(fmaxf(v[0], v[1]), fmaxf(v[2], v[3]));
#pragma unroll
  for (int off = 32; off; off >>= 1) mx = fmaxf(mx, __shfl_xor(mx, off));
  __shared__ float red[4];
  __shared__ float red2[4];
  if (lane == 0) red[wid] = mx;
  __syncthreads();
  mx = fmaxf(fmaxf(red[0], red[1]), fmaxf(red[2], red[3]));
  const float e0 = __expf(v[0] - mx), e1 = __expf(v[1] - mx);
  const float e2 = __expf(v[2] - mx), e3 = __expf(v[3] - mx);
  float s = (e0 + e1) + (e2 + e3);
#pragma unroll
  for (int off = 32; off; off >>= 1) s += __shfl_xor(s, off);
  if (lane == 0) red2[wid] = s;
  __syncthreads();
  const float inv = 1.0f / (red2[0] + red2[1] + red2[2] + red2[3]);
  u16x4 o;
  o[0] = f2bf(e0 * inv); o[1] = f2bf(e1 * inv); o[2] = f2bf(e2 * inv); o[3] = f2bf(e3 * inv);
  ((u16x4*)rp)[tid] = o;  // bytes [0,2048) of this row's own 4096B span: race-free
}

// ---------------- ctx[b] = attn[b] @ hidden[b], bf16 out, XCD-swizzled ----------------
// hidden in [s][h] layout -> transpose-staged to LDS [h][s].
__global__ __launch_bounds__(256) void gemm_ctx_k(
    const u16* __restrict__ Attn, const u16* __restrict__ H, u16* __restrict__ Ctx) {
  const int wg = blockIdx.x;
  const int swz = (wg & 7) * 128 + (wg >> 3);
  const int z = swz >> 5;
  const int n0 = ((swz >> 2) & 7) * 128;
  const int m0 = (swz & 3) * 128;
  const u16* A = Attn + (size_t)z * 512 * 2048;
  const u16* B = H + (size_t)z * 1024 * 1024;

  __shared__ u16 As[128 * 32];
  __shared__ u16 Bs[128 * 40];  // [h 128][s 32] pitch 40
  const int tid = threadIdx.x;
  const int lane = tid & 63, wid = tid >> 6;
  const int wr = wid >> 1, wc = wid & 1;

  f32x4 acc[4][4] = {};
  const int r_in = lane >> 2;
  const int c8 = (lane & 3) * 8;

  for (int kt = 0; kt < 32; ++kt) {
    const int k0 = kt * 32;
    __syncthreads();
#pragma unroll
    for (int i = 0; i < 2; ++i) {
      const int ch = wid + i * 4;
      const int row = ch * 16 + r_in;
      gload16(A + (size_t)(m0 + row) * 2048 + k0 + c8, &As[ch * 512]);
    }
#pragma unroll
    for (int i = 0; i < 2; ++i) {
      const int s = i * 16 + (tid >> 4);
      const int h0 = (tid & 15) * 8;
      union { u32x4 v; u16 u[8]; } r;
      r.v = *(const u32x4*)(B + (size_t)(k0 + s) * 1024 + n0 + h0);
#pragma unroll
      for (int j = 0; j < 8; ++j) Bs[(h0 + j) * 40 + s] = r.u[j];
    }
    __syncthreads();
    short8 af[4], bfr[4];
#pragma unroll
    for (int m = 0; m < 4; ++m)
      af[m] = *(const short8*)&As[(wr * 64 + m * 16 + (lane & 15)) * 32 + (lane >> 4) * 8];
#pragma unroll
    for (int n = 0; n < 4; ++n)
      bfr[n] = *(const short8*)&Bs[(wc * 64 + n * 16 + (lane & 15)) * 40 + (lane >> 4) * 8];
#pragma unroll
    for (int m = 0; m < 4; ++m)
#pragma unroll
      for (int n = 0; n < 4; ++n)
        acc[m][n] = __builtin_amdgcn_mfma_f32_16x16x32_bf16(af[m], bfr[n], acc[m][n], 0, 0, 0);
  }

  u16* C = Ctx + (size_t)z * 512 * 1024;
  const int cb = n0 + wc * 64 + (lane & 15);
  const int rb = m0 + wr * 64 + (lane >> 4) * 4;
#pragma unroll
  for (int n = 0; n < 4; ++n) {
    const int col = cb + n * 16;
#pragma unroll
    for (int m = 0; m < 4; ++m) {
      const int row = rb + m * 16;
#pragma unroll
      for (int j = 0; j < 4; ++j)
        C[(size_t)(row + j) * 1024 + col] = f2bf(acc[m][n][j]);
    }
  }
}

// ---------------- out = sigmoid(ctx @ V_w^T + V_b), f32 out ----------------
// M=16384, N=1024, K=1024. Grid (128, 8). V_w row-major [j][h]: h contiguous -> direct Bt.
__global__ __launch_bounds__(256) void gemm_out_k(
    const u16* __restrict__ A, const u16* __restrict__ Bt,
    const float* __restrict__ bias, float* __restrict__ C) {
  __shared__ u16 As[128 * 32];
  __shared__ u16 Bs[128 * 32];
  const int tid = threadIdx.x;
  const int lane = tid & 63, wid = tid >> 6;
  const int wr = wid >> 1, wc = wid & 1;
  const int m0 = blockIdx.x * 128;
  const int n0 = blockIdx.y * 128;

  f32x4 acc[4][4] = {};
  const int r_in = lane >> 2;
  const int c8 = (lane & 3) * 8;

  for (int kt = 0; kt < 32; ++kt) {
    const int k0 = kt * 32;
    __syncthreads();
#pragma unroll
    for (int i = 0; i < 2; ++i) {
      const int ch = wid + i * 4;
      const int row = ch * 16 + r_in;
      gload16(A + (size_t)(m0 + row) * 1024 + k0 + c8, &As[ch * 512]);
      gload16(Bt + (size_t)(n0 + row) * 1024 + k0 + c8, &Bs[ch * 512]);
    }
    __syncthreads();
    short8 af[4], bfr[4];
#pragma unroll
    for (int m = 0; m < 4; ++m)
      af[m] = *(const short8*)&As[(wr * 64 + m * 16 + (lane & 15)) * 32 + (lane >> 4) * 8];
#pragma unroll
    for (int n = 0; n < 4; ++n)
      bfr[n] = *(const short8*)&Bs[(wc * 64 + n * 16 + (lane & 15)) * 32 + (lane >> 4) * 8];
#pragma unroll
    for (int m = 0; m < 4; ++m)
#pragma unroll
      for (int n = 0; n < 4; ++n)
        acc[m][n] = __builtin_amdgcn_mfma_f32_16x16x32_bf16(af[m], bfr[n], acc[m][n], 0, 0, 0);
  }

  const int cb = n0 + wc * 64 + (lane & 15);
  const int rb = m0 + wr * 64 + (lane >> 4) * 4;
#pragma unroll
  for (int n = 0; n < 4; ++n) {
    const int col = cb + n * 16;
    const float bv = bias[col];
#pragma unroll
    for (int m = 0; m < 4; ++m) {
      const int row = rb + m * 16;
#pragma unroll
      for (int j = 0; j < 4; ++j) {
        const float x = acc[m][n][j] + bv;
        C[(size_t)(row + j) * 1024 + col] = 1.0f / (1.0f + __expf(-x));
      }
    }
  }
}

// ---------------- launch ----------------
// Shapes: S=1024, B=32, H=1024, T=512.
// Reassociated (softmax shift-invariance + attn row-sum=1):
//   q'  = x @ K_w                      [B*T, H]   (split 3-pass; K_b dropped — per-row const)
//   scr = q'[b] @ hidden[b]^T          [B, T, S]  (split 3-pass)
//   attn = softmax(scr)                           (bf16 in-place)
//   ctx = attn[b] @ hidden[b]          [B, T, H]  (bf16)
//   out = sigmoid(ctx @ V_w^T + V_b)   [B, T, H]  (f32)
// ws layout (bytes), total ~294MB:
//   hhi @ 0         : 64MB   hlo @ 64MB : 64MB
//   qhi @ 128MB     : 32MB   qlo @ 160MB: 32MB
//   scores @ 192MB  : 64MB f32 (-> attn bf16 in place, row stride 2048 u16)
//   ctx @ 256MB     : 32MB bf16
//   w @ 288MB       : kwt_hi 2MB | kwt_lo 2MB | vw 2MB
// x split bf16 lives in d_out (dead before final out GEMM overwrites it).
extern "C" void kernel_launch(void* const* d_in, const int* in_sizes, int n_in,
                              void* d_out, int out_size, void* d_ws, size_t ws_size,
                              hipStream_t stream) {
  const float* hidden = (const float*)d_in[0];
  const float* x = (const float*)d_in[1];
  // d_in[2] problem_q unused; d_in[4] K_b dropped (softmax shift invariance)
  const float* K_w = (const float*)d_in[3];
  const float* V_w = (const float*)d_in[5];
  const float* V_b = (const float*)d_in[6];

  char* ws = (char*)d_ws;
  u16* hhi = (u16*)(ws);
  u16* hlo = (u16*)(ws + 67108864);
  u16* qhi = (u16*)(ws + 134217728);
  u16* qlo = (u16*)(ws + 167772160);
  float* scoresF = (float*)(ws + 201326592);
  u16* ctx = (u16*)(ws + 268435456);
  u16* kwt_h = (u16*)(ws + 301989888);
  u16* kwt_l = kwt_h + 1024 * 1024;
  u16* vw = kwt_h + 2 * 1024 * 1024;
  u16* xhi = (u16*)d_out;
  u16* xlo = xhi + 32L * 512 * 1024;
  float* out = (float*)d_out;

  // 1. hidden [S,B,H] -> split bf16 [B,S,H]
  cvt_hidden_split_k<<<dim3(1024, 32), 256, 0, stream>>>(hidden, hhi, hlo);
  // 2. x -> split bf16 (into d_out)
  cvt_split_k<<<2048, 256, 0, stream>>>(x, xhi, xlo, 32L * 512 * 1024 / 4);
  // 3. weights: K_w transposed split, V_w single (row-major already Bt-shaped)
  cvt_w_split_t_k<<<dim3(16, 16), 256, 0, stream>>>(K_w, kwt_h, kwt_l);
  cvt_f32_bf16_k<<<1024, 256, 0, stream>>>(V_w, vw, 1024L * 1024 / 4);
  // 4. q' = x @ K_w  (split 3-pass, split out)
  gemm3_qp_k<<<dim3(128, 8), 256, 0, stream>>>(xhi, xlo, kwt_h, kwt_l, qhi, qlo);
  // 5. scores[b] = q'[b] @ hidden[b]^T  (split 3-pass, f32 out, XCD-swizzled)
  gemm3_scores_k<<<1024, 256, 0, stream>>>(qhi, qlo, hhi, hlo, scoresF);
  // 6. softmax over S, bf16 attn in place (row stride 2048 u16)
  softmax_k<<<16384, 256, 0, stream>>>(scoresF);
  // 7. ctx[b] = attn[b] @ hidden[b]  (bf16, XCD-swizzled)
  gemm_ctx_k<<<1024, 256, 0, stream>>>((const u16*)scoresF, hhi, ctx);
  // 8. out = sigmoid(ctx @ V_w^T + V_b)
  gemm_out_k<<<dim3(128, 8), 256, 0, stream>>>(ctx, vw, V_b, out);
}

// Round 4
// 496.566 us; speedup vs baseline: 1.5330x; 1.1494x over previous
//
#include <hip/hip_runtime.h>

typedef unsigned short u16;
typedef __attribute__((ext_vector_type(8))) short short8;
typedef __attribute__((ext_vector_type(4))) float f32x4;
typedef __attribute__((ext_vector_type(4))) u16 u16x4;
typedef __attribute__((ext_vector_type(4))) unsigned int u32x4;

#define DEVINL static __device__ __forceinline__

DEVINL u16 f2bf(float f) {
  unsigned u = __builtin_bit_cast(unsigned, f);
  u += 0x7fffu + ((u >> 16) & 1u);
  return (u16)(u >> 16);
}
DEVINL float bf2f(u16 h) {
  return __builtin_bit_cast(float, ((unsigned)h) << 16);
}

// async global->LDS, 16B per lane; lds base must be wave-uniform
DEVINL void gload16(const void* g, void* l) {
  __builtin_amdgcn_global_load_lds(
      (const __attribute__((address_space(1))) void*)g,
      (__attribute__((address_space(3))) void*)l, 16, 0, 0);
}

// ---------------- converts ----------------

// hidden [S=1024, B=32, H=1024] f32 -> hhi/hlo [B, S, H] split bf16
__global__ __launch_bounds__(256) void cvt_hidden_split_k(const float* __restrict__ hid,
                                                          u16* __restrict__ hhi,
                                                          u16* __restrict__ hlo) {
  const int s = blockIdx.x;
  const int b = blockIdx.y;
  const int t = threadIdx.x;
  const f32x4 v = ((const f32x4*)(hid + ((size_t)s * 32 + b) * 1024))[t];
  u16x4 oh, ol;
#pragma unroll
  for (int j = 0; j < 4; ++j) {
    const u16 hi = f2bf(v[j]);
    oh[j] = hi;
    ol[j] = f2bf(v[j] - bf2f(hi));
  }
  const size_t base = ((size_t)b * 1024 + s) * 1024;
  ((u16x4*)(hhi + base))[t] = oh;
  ((u16x4*)(hlo + base))[t] = ol;
}

// generic f32 -> split bf16 (hi, lo)
__global__ __launch_bounds__(256) void cvt_split_k(const float* __restrict__ in,
                                                   u16* __restrict__ hi_o,
                                                   u16* __restrict__ lo_o, long n4) {
  long i = (long)blockIdx.x * 256 + threadIdx.x;
  const long stride = (long)gridDim.x * 256;
  for (; i < n4; i += stride) {
    const f32x4 v = ((const f32x4*)in)[i];
    u16x4 oh, ol;
#pragma unroll
    for (int j = 0; j < 4; ++j) {
      const u16 hi = f2bf(v[j]);
      oh[j] = hi;
      ol[j] = f2bf(v[j] - bf2f(hi));
    }
    ((u16x4*)hi_o)[i] = oh;
    ((u16x4*)lo_o)[i] = ol;
  }
}

// generic f32 -> bf16 (single)
__global__ __launch_bounds__(256) void cvt_f32_bf16_k(const float* __restrict__ in,
                                                      u16* __restrict__ out, long n4) {
  long i = (long)blockIdx.x * 256 + threadIdx.x;
  const long stride = (long)gridDim.x * 256;
  for (; i < n4; i += stride) {
    const f32x4 v = ((const f32x4*)in)[i];
    u16x4 o;
#pragma unroll
    for (int j = 0; j < 4; ++j) o[j] = f2bf(v[j]);
    ((u16x4*)out)[i] = o;
  }
}

// K_w [j=1024][h=1024] f32 -> transposed split bf16: out[h][j]
__global__ __launch_bounds__(256) void cvt_w_split_t_k(const float* __restrict__ in,
                                                       u16* __restrict__ hi_o,
                                                       u16* __restrict__ lo_o) {
  __shared__ float tile[64][65];
  const int bh = blockIdx.x * 64;
  const int bj = blockIdx.y * 64;
  const int t = threadIdx.x;
  const int r = t >> 4;
  const int c4 = (t & 15) * 4;
#pragma unroll
  for (int it = 0; it < 4; ++it) {
    const int row = it * 16 + r;
    const f32x4 v = *(const f32x4*)(in + (size_t)(bj + row) * 1024 + bh + c4);
#pragma unroll
    for (int j = 0; j < 4; ++j) tile[c4 + j][row] = v[j];
  }
  __syncthreads();
#pragma unroll
  for (int it = 0; it < 4; ++it) {
    const int hrow = it * 16 + r;
    u16x4 oh, ol;
#pragma unroll
    for (int j = 0; j < 4; ++j) {
      const float f = tile[hrow][c4 + j];
      const u16 hv = f2bf(f);
      oh[j] = hv;
      ol[j] = f2bf(f - bf2f(hv));
    }
    *(u16x4*)(hi_o + (size_t)(bh + hrow) * 1024 + bj + c4) = oh;
    *(u16x4*)(lo_o + (size_t)(bh + hrow) * 1024 + bj + c4) = ol;
  }
}

// ---------------- split-precision 3-pass GEMM: C = (Ah+Al)*(Bh+Bl)^T, split bf16 out ----------------
// q' = x @ K_w (via pre-transposed weights). M=16384, N=1024, K=1024. Grid (M/128, 8).
__global__ __launch_bounds__(256) void gemm3_qp_k(
    const u16* __restrict__ Ah, const u16* __restrict__ Al,
    const u16* __restrict__ Bh, const u16* __restrict__ Bl,
    u16* __restrict__ Chi, u16* __restrict__ Clo) {
  __shared__ u16 Ash[128 * 32];
  __shared__ u16 Asl[128 * 32];
  __shared__ u16 Bsh[128 * 32];
  __shared__ u16 Bsl[128 * 32];
  const int tid = threadIdx.x;
  const int lane = tid & 63, wid = tid >> 6;
  const int wr = wid >> 1, wc = wid & 1;
  const int m0 = blockIdx.x * 128;
  const int n0 = blockIdx.y * 128;

  f32x4 acc[4][4] = {};
  const int r_in = lane >> 2;
  const int c8 = (lane & 3) * 8;

  for (int kt = 0; kt < 32; ++kt) {
    const int k0 = kt * 32;
    __syncthreads();
#pragma unroll
    for (int i = 0; i < 2; ++i) {
      const int ch = wid + i * 4;
      const int row = ch * 16 + r_in;
      const size_t ga = (size_t)(m0 + row) * 1024 + k0 + c8;
      const size_t gb = (size_t)(n0 + row) * 1024 + k0 + c8;
      gload16(Ah + ga, &Ash[ch * 512]);
      gload16(Al + ga, &Asl[ch * 512]);
      gload16(Bh + gb, &Bsh[ch * 512]);
      gload16(Bl + gb, &Bsl[ch * 512]);
    }
    __syncthreads();
    short8 ah[4], al[4], bh[4], bl[4];
#pragma unroll
    for (int m = 0; m < 4; ++m) {
      const int off = (wr * 64 + m * 16 + (lane & 15)) * 32 + (lane >> 4) * 8;
      ah[m] = *(const short8*)&Ash[off];
      al[m] = *(const short8*)&Asl[off];
    }
#pragma unroll
    for (int n = 0; n < 4; ++n) {
      const int off = (wc * 64 + n * 16 + (lane & 15)) * 32 + (lane >> 4) * 8;
      bh[n] = *(const short8*)&Bsh[off];
      bl[n] = *(const short8*)&Bsl[off];
    }
#pragma unroll
    for (int m = 0; m < 4; ++m)
#pragma unroll
      for (int n = 0; n < 4; ++n) {
        acc[m][n] = __builtin_amdgcn_mfma_f32_16x16x32_bf16(ah[m], bh[n], acc[m][n], 0, 0, 0);
        acc[m][n] = __builtin_amdgcn_mfma_f32_16x16x32_bf16(ah[m], bl[n], acc[m][n], 0, 0, 0);
        acc[m][n] = __builtin_amdgcn_mfma_f32_16x16x32_bf16(al[m], bh[n], acc[m][n], 0, 0, 0);
      }
  }

  const int cb = n0 + wc * 64 + (lane & 15);
  const int rb = m0 + wr * 64 + (lane >> 4) * 4;
#pragma unroll
  for (int n = 0; n < 4; ++n) {
    const int col = cb + n * 16;
#pragma unroll
    for (int m = 0; m < 4; ++m) {
      const int row = rb + m * 16;
#pragma unroll
      for (int j = 0; j < 4; ++j) {
        const float kv = acc[m][n][j];
        const u16 hi = f2bf(kv);
        Chi[(size_t)(row + j) * 1024 + col] = hi;
        Clo[(size_t)(row + j) * 1024 + col] = f2bf(kv - bf2f(hi));
      }
    }
  }
}

// ---------------- scores[b] = q'[b] @ hidden[b]^T, 3-pass split, f32 out, XCD-swizzled ----------------
__global__ __launch_bounds__(256) void gemm3_scores_k(
    const u16* __restrict__ Qh, const u16* __restrict__ Ql,
    const u16* __restrict__ Hh, const u16* __restrict__ Hl,
    float* __restrict__ S) {
  const int wg = blockIdx.x;
  const int swz = (wg & 7) * 128 + (wg >> 3);  // bijective, 1024 = 8*128
  const int z = swz >> 5;
  const int n0 = ((swz >> 2) & 7) * 128;
  const int m0 = (swz & 3) * 128;
  const u16* Ah = Qh + (size_t)z * 512 * 1024;
  const u16* Al = Ql + (size_t)z * 512 * 1024;
  const u16* Bh = Hh + (size_t)z * 1024 * 1024;
  const u16* Bl = Hl + (size_t)z * 1024 * 1024;

  __shared__ u16 Ash[128 * 32];
  __shared__ u16 Asl[128 * 32];
  __shared__ u16 Bsh[128 * 32];
  __shared__ u16 Bsl[128 * 32];
  const int tid = threadIdx.x;
  const int lane = tid & 63, wid = tid >> 6;
  const int wr = wid >> 1, wc = wid & 1;

  f32x4 acc[4][4] = {};
  const int r_in = lane >> 2;
  const int c8 = (lane & 3) * 8;

  for (int kt = 0; kt < 32; ++kt) {
    const int k0 = kt * 32;
    __syncthreads();
#pragma unroll
    for (int i = 0; i < 2; ++i) {
      const int ch = wid + i * 4;
      const int row = ch * 16 + r_in;
      const size_t ga = (size_t)(m0 + row) * 1024 + k0 + c8;
      const size_t gb = (size_t)(n0 + row) * 1024 + k0 + c8;
      gload16(Ah + ga, &Ash[ch * 512]);
      gload16(Al + ga, &Asl[ch * 512]);
      gload16(Bh + gb, &Bsh[ch * 512]);
      gload16(Bl + gb, &Bsl[ch * 512]);
    }
    __syncthreads();
    short8 ah[4], al[4], bh[4], bl[4];
#pragma unroll
    for (int m = 0; m < 4; ++m) {
      const int off = (wr * 64 + m * 16 + (lane & 15)) * 32 + (lane >> 4) * 8;
      ah[m] = *(const short8*)&Ash[off];
      al[m] = *(const short8*)&Asl[off];
    }
#pragma unroll
    for (int n = 0; n < 4; ++n) {
      const int off = (wc * 64 + n * 16 + (lane & 15)) * 32 + (lane >> 4) * 8;
      bh[n] = *(const short8*)&Bsh[off];
      bl[n] = *(const short8*)&Bsl[off];
    }
#pragma unroll
    for (int m = 0; m < 4; ++m)
#pragma unroll
      for (int n = 0; n < 4; ++n) {
        acc[m][n] = __builtin_amdgcn_mfma_f32_16x16x32_bf16(ah[m], bh[n], acc[m][n], 0, 0, 0);
        acc[m][n] = __builtin_amdgcn_mfma_f32_16x16x32_bf16(ah[m], bl[n], acc[m][n], 0, 0, 0);
        acc[m][n] = __builtin_amdgcn_mfma_f32_16x16x32_bf16(al[m], bh[n], acc[m][n], 0, 0, 0);
      }
  }

  float* C = S + (size_t)z * 512 * 1024;
  const int cb = n0 + wc * 64 + (lane & 15);
  const int rb = m0 + wr * 64 + (lane >> 4) * 4;
#pragma unroll
  for (int n = 0; n < 4; ++n) {
    const int col = cb + n * 16;
#pragma unroll
    for (int m = 0; m < 4; ++m) {
      const int row = rb + m * 16;
#pragma unroll
      for (int j = 0; j < 4; ++j)
        C[(size_t)(row + j) * 1024 + col] = acc[m][n][j];
    }
  }
}

// ---------------- softmax over last dim (1024), writes compact bf16 attn ----------------
__global__ __launch_bounds__(256) void softmax_k(const float* __restrict__ S,
                                                 u16* __restrict__ Attn) {
  const float* rp = S + (size_t)blockIdx.x * 1024;
  const int tid = threadIdx.x;
  const int lane = tid & 63, wid = tid >> 6;
  const f32x4 v = ((const f32x4*)rp)[tid];
  float mx = fmaxf(fmaxf(v[0], v[1]), fmaxf(v[2], v[3]));
#pragma unroll
  for (int off = 32; off; off >>= 1) mx = fmaxf(mx, __shfl_xor(mx, off));
  __shared__ float red[4];
  __shared__ float red2[4];
  if (lane == 0) red[wid] = mx;
  __syncthreads();
  mx = fmaxf(fmaxf(red[0], red[1]), fmaxf(red[2], red[3]));
  const float e0 = __expf(v[0] - mx), e1 = __expf(v[1] - mx);
  const float e2 = __expf(v[2] - mx), e3 = __expf(v[3] - mx);
  float s = (e0 + e1) + (e2 + e3);
#pragma unroll
  for (int off = 32; off; off >>= 1) s += __shfl_xor(s, off);
  if (lane == 0) red2[wid] = s;
  __syncthreads();
  const float inv = 1.0f / (red2[0] + red2[1] + red2[2] + red2[3]);
  u16x4 o;
  o[0] = f2bf(e0 * inv); o[1] = f2bf(e1 * inv); o[2] = f2bf(e2 * inv); o[3] = f2bf(e3 * inv);
  ((u16x4*)(Attn + (size_t)blockIdx.x * 1024))[tid] = o;
}

// ---------------- ctx[b] = attn[b] @ hidden[b], bf16 out, XCD-swizzled ----------------
// hidden [s][h] transpose-staged to LDS [h][s] with XOR-swizzle:
//   rows padded to 128B (pitch 64 u16), key = ((h>>3)^h)&7, byte ^= key<<4.
//   write: 4-way banks (was 16-way); read: 2-way (free). Bijective: rows 128B-aligned,
//   XOR confined to bits 4-6 => stays within own row.
__global__ __launch_bounds__(256) void gemm_ctx_k(
    const u16* __restrict__ Attn, const u16* __restrict__ H, u16* __restrict__ Ctx) {
  const int wg = blockIdx.x;
  const int swz = (wg & 7) * 128 + (wg >> 3);
  const int z = swz >> 5;
  const int n0 = ((swz >> 2) & 7) * 128;
  const int m0 = (swz & 3) * 128;
  const u16* A = Attn + (size_t)z * 512 * 1024;
  const u16* B = H + (size_t)z * 1024 * 1024;

  __shared__ u16 As[128 * 32];
  __shared__ u16 Bs[128 * 64];  // [h 128][s 32 of 64], swizzled
  const int tid = threadIdx.x;
  const int lane = tid & 63, wid = tid >> 6;
  const int wr = wid >> 1, wc = wid & 1;

  f32x4 acc[4][4] = {};
  const int r_in = lane >> 2;
  const int c8 = (lane & 3) * 8;

  for (int kt = 0; kt < 32; ++kt) {
    const int k0 = kt * 32;
    __syncthreads();
#pragma unroll
    for (int i = 0; i < 2; ++i) {
      const int ch = wid + i * 4;
      const int row = ch * 16 + r_in;
      gload16(A + (size_t)(m0 + row) * 1024 + k0 + c8, &As[ch * 512]);
    }
#pragma unroll
    for (int i = 0; i < 2; ++i) {
      const int s = i * 16 + (tid >> 4);
      const int h0 = (tid & 15) * 8;
      union { u32x4 v; u16 u[8]; } r;
      r.v = *(const u32x4*)(B + (size_t)(k0 + s) * 1024 + n0 + h0);
#pragma unroll
      for (int j = 0; j < 8; ++j) {
        const int h = h0 + j;
        const int key = ((h >> 3) ^ h) & 7;
        Bs[h * 64 + (((s * 2) ^ (key << 4)) >> 1)] = r.u[j];
      }
    }
    __syncthreads();
    short8 af[4], bfr[4];
#pragma unroll
    for (int m = 0; m < 4; ++m)
      af[m] = *(const short8*)&As[(wr * 64 + m * 16 + (lane & 15)) * 32 + (lane >> 4) * 8];
#pragma unroll
    for (int n = 0; n < 4; ++n) {
      const int row = wc * 64 + n * 16 + (lane & 15);
      const int key = ((row >> 3) ^ row) & 7;
      const int boff = (((lane >> 4) * 16) ^ (key << 4)) >> 1;  // u16 units, 16B-aligned
      bfr[n] = *(const short8*)&Bs[row * 64 + boff];
    }
#pragma unroll
    for (int m = 0; m < 4; ++m)
#pragma unroll
      for (int n = 0; n < 4; ++n)
        acc[m][n] = __builtin_amdgcn_mfma_f32_16x16x32_bf16(af[m], bfr[n], acc[m][n], 0, 0, 0);
  }

  u16* C = Ctx + (size_t)z * 512 * 1024;
  const int cb = n0 + wc * 64 + (lane & 15);
  const int rb = m0 + wr * 64 + (lane >> 4) * 4;
#pragma unroll
  for (int n = 0; n < 4; ++n) {
    const int col = cb + n * 16;
#pragma unroll
    for (int m = 0; m < 4; ++m) {
      const int row = rb + m * 16;
#pragma unroll
      for (int j = 0; j < 4; ++j)
        C[(size_t)(row + j) * 1024 + col] = f2bf(acc[m][n][j]);
    }
  }
}

// ---------------- out = sigmoid(ctx @ V_w^T + V_b), f32 out ----------------
__global__ __launch_bounds__(256) void gemm_out_k(
    const u16* __restrict__ A, const u16* __restrict__ Bt,
    const float* __restrict__ bias, float* __restrict__ C) {
  __shared__ u16 As[128 * 32];
  __shared__ u16 Bs[128 * 32];
  const int tid = threadIdx.x;
  const int lane = tid & 63, wid = tid >> 6;
  const int wr = wid >> 1, wc = wid & 1;
  const int m0 = blockIdx.x * 128;
  const int n0 = blockIdx.y * 128;

  f32x4 acc[4][4] = {};
  const int r_in = lane >> 2;
  const int c8 = (lane & 3) * 8;

  for (int kt = 0; kt < 32; ++kt) {
    const int k0 = kt * 32;
    __syncthreads();
#pragma unroll
    for (int i = 0; i < 2; ++i) {
      const int ch = wid + i * 4;
      const int row = ch * 16 + r_in;
      gload16(A + (size_t)(m0 + row) * 1024 + k0 + c8, &As[ch * 512]);
      gload16(Bt + (size_t)(n0 + row) * 1024 + k0 + c8, &Bs[ch * 512]);
    }
    __syncthreads();
    short8 af[4], bfr[4];
#pragma unroll
    for (int m = 0; m < 4; ++m)
      af[m] = *(const short8*)&As[(wr * 64 + m * 16 + (lane & 15)) * 32 + (lane >> 4) * 8];
#pragma unroll
    for (int n = 0; n < 4; ++n)
      bfr[n] = *(const short8*)&Bs[(wc * 64 + n * 16 + (lane & 15)) * 32 + (lane >> 4) * 8];
#pragma unroll
    for (int m = 0; m < 4; ++m)
#pragma unroll
      for (int n = 0; n < 4; ++n)
        acc[m][n] = __builtin_amdgcn_mfma_f32_16x16x32_bf16(af[m], bfr[n], acc[m][n], 0, 0, 0);
  }

  const int cb = n0 + wc * 64 + (lane & 15);
  const int rb = m0 + wr * 64 + (lane >> 4) * 4;
#pragma unroll
  for (int n = 0; n < 4; ++n) {
    const int col = cb + n * 16;
    const float bv = bias[col];
#pragma unroll
    for (int m = 0; m < 4; ++m) {
      const int row = rb + m * 16;
#pragma unroll
      for (int j = 0; j < 4; ++j) {
        const float x = acc[m][n][j] + bv;
        C[(size_t)(row + j) * 1024 + col] = 1.0f / (1.0f + __expf(-x));
      }
    }
  }
}

// ---------------- launch ----------------
// Shapes: S=1024, B=32, H=1024, T=512.
//   q'  = x @ K_w                      (split 3-pass; K_b dropped — softmax shift-invariant)
//   scr = q'[b] @ hidden[b]^T          (split 3-pass, f32)
//   attn = softmax(scr)                (compact bf16 [B,T,S])
//   ctx = attn[b] @ hidden[b]          (bf16, swizzled transpose-staging)
//   out = sigmoid(ctx @ V_w^T + V_b)   (f32)
// ws layout (MB): hhi 0-64 | hlo 64-128 | qhi 128-160 | qlo 160-192 |
//   scores f32 192-256 | attn bf16 256-288 | ctx bf16 288-320 | weights 320-326
extern "C" void kernel_launch(void* const* d_in, const int* in_sizes, int n_in,
                              void* d_out, int out_size, void* d_ws, size_t ws_size,
                              hipStream_t stream) {
  const float* hidden = (const float*)d_in[0];
  const float* x = (const float*)d_in[1];
  // d_in[2] problem_q unused; d_in[4] K_b dropped (softmax shift invariance)
  const float* K_w = (const float*)d_in[3];
  const float* V_w = (const float*)d_in[5];
  const float* V_b = (const float*)d_in[6];

  char* ws = (char*)d_ws;
  u16* hhi = (u16*)(ws);
  u16* hlo = (u16*)(ws + 67108864);
  u16* qhi = (u16*)(ws + 134217728);
  u16* qlo = (u16*)(ws + 167772160);
  float* scoresF = (float*)(ws + 201326592);
  u16* attn = (u16*)(ws + 268435456);
  u16* ctx = (u16*)(ws + 301989888);
  u16* kwt_h = (u16*)(ws + 335544320);
  u16* kwt_l = kwt_h + 1024 * 1024;
  u16* vw = kwt_h + 2 * 1024 * 1024;
  u16* xhi = (u16*)d_out;
  u16* xlo = xhi + 32L * 512 * 1024;
  float* out = (float*)d_out;

  // 1. hidden [S,B,H] -> split bf16 [B,S,H]
  cvt_hidden_split_k<<<dim3(1024, 32), 256, 0, stream>>>(hidden, hhi, hlo);
  // 2. x -> split bf16 (into d_out; dead before final GEMM overwrites it)
  cvt_split_k<<<2048, 256, 0, stream>>>(x, xhi, xlo, 32L * 512 * 1024 / 4);
  // 3. weights: K_w transposed split, V_w single
  cvt_w_split_t_k<<<dim3(16, 16), 256, 0, stream>>>(K_w, kwt_h, kwt_l);
  cvt_f32_bf16_k<<<1024, 256, 0, stream>>>(V_w, vw, 1024L * 1024 / 4);
  // 4. q' = x @ K_w  (split 3-pass, split out)
  gemm3_qp_k<<<dim3(128, 8), 256, 0, stream>>>(xhi, xlo, kwt_h, kwt_l, qhi, qlo);
  // 5. scores[b] = q'[b] @ hidden[b]^T  (split 3-pass, f32 out, XCD-swizzled)
  gemm3_scores_k<<<1024, 256, 0, stream>>>(qhi, qlo, hhi, hlo, scoresF);
  // 6. softmax over S -> compact bf16 attn
  softmax_k<<<16384, 256, 0, stream>>>(scoresF, attn);
  // 7. ctx[b] = attn[b] @ hidden[b]  (bf16, XCD-swizzled, conflict-fixed staging)
  gemm_ctx_k<<<1024, 256, 0, stream>>>(attn, hhi, ctx);
  // 8. out = sigmoid(ctx @ V_w^T + V_b)
  gemm_out_k<<<dim3(128, 8), 256, 0, stream>>>(ctx, vw, V_b, out);
}

// Round 5
// 443.695 us; speedup vs baseline: 1.7157x; 1.1192x over previous
//
#include <hip/hip_runtime.h>

typedef unsigned short u16;
typedef __attribute__((ext_vector_type(8))) short short8;
typedef __attribute__((ext_vector_type(4))) float f32x4;
typedef __attribute__((ext_vector_type(4))) u16 u16x4;
typedef __attribute__((ext_vector_type(4))) unsigned int u32x4;

#define DEVINL static __device__ __forceinline__

DEVINL u16 f2bf(float f) {
  unsigned u = __builtin_bit_cast(unsigned, f);
  u += 0x7fffu + ((u >> 16) & 1u);
  return (u16)(u >> 16);
}
DEVINL float bf2f(u16 h) {
  return __builtin_bit_cast(float, ((unsigned)h) << 16);
}

// async global->LDS, 16B per lane; lds base must be wave-uniform
DEVINL void gload16(const void* g, void* l) {
  __builtin_amdgcn_global_load_lds(
      (const __attribute__((address_space(1))) void*)g,
      (__attribute__((address_space(3))) void*)l, 16, 0, 0);
}

#define BAR() asm volatile("s_barrier" ::: "memory")
#define WAIT_VM0() asm volatile("s_waitcnt vmcnt(0)" ::: "memory")
#define WAIT_LGKM0() asm volatile("s_waitcnt lgkmcnt(0)" ::: "memory")

// ---------------- converts ----------------

// hidden [S=1024, B=32, H=1024] f32 -> hhi/hlo [B, S, H] split bf16
__global__ __launch_bounds__(256) void cvt_hidden_split_k(const float* __restrict__ hid,
                                                          u16* __restrict__ hhi,
                                                          u16* __restrict__ hlo) {
  const int s = blockIdx.x;
  const int b = blockIdx.y;
  const int t = threadIdx.x;
  const f32x4 v = ((const f32x4*)(hid + ((size_t)s * 32 + b) * 1024))[t];
  u16x4 oh, ol;
#pragma unroll
  for (int j = 0; j < 4; ++j) {
    const u16 hi = f2bf(v[j]);
    oh[j] = hi;
    ol[j] = f2bf(v[j] - bf2f(hi));
  }
  const size_t base = ((size_t)b * 1024 + s) * 1024;
  ((u16x4*)(hhi + base))[t] = oh;
  ((u16x4*)(hlo + base))[t] = ol;
}

// generic f32 -> split bf16 (hi, lo)
__global__ __launch_bounds__(256) void cvt_split_k(const float* __restrict__ in,
                                                   u16* __restrict__ hi_o,
                                                   u16* __restrict__ lo_o, long n4) {
  long i = (long)blockIdx.x * 256 + threadIdx.x;
  const long stride = (long)gridDim.x * 256;
  for (; i < n4; i += stride) {
    const f32x4 v = ((const f32x4*)in)[i];
    u16x4 oh, ol;
#pragma unroll
    for (int j = 0; j < 4; ++j) {
      const u16 hi = f2bf(v[j]);
      oh[j] = hi;
      ol[j] = f2bf(v[j] - bf2f(hi));
    }
    ((u16x4*)hi_o)[i] = oh;
    ((u16x4*)lo_o)[i] = ol;
  }
}

// generic f32 -> bf16 (single)
__global__ __launch_bounds__(256) void cvt_f32_bf16_k(const float* __restrict__ in,
                                                      u16* __restrict__ out, long n4) {
  long i = (long)blockIdx.x * 256 + threadIdx.x;
  const long stride = (long)gridDim.x * 256;
  for (; i < n4; i += stride) {
    const f32x4 v = ((const f32x4*)in)[i];
    u16x4 o;
#pragma unroll
    for (int j = 0; j < 4; ++j) o[j] = f2bf(v[j]);
    ((u16x4*)out)[i] = o;
  }
}

// K_w [j=1024][h=1024] f32 -> transposed split bf16: out[h][j]
__global__ __launch_bounds__(256) void cvt_w_split_t_k(const float* __restrict__ in,
                                                       u16* __restrict__ hi_o,
                                                       u16* __restrict__ lo_o) {
  __shared__ float tile[64][65];
  const int bh = blockIdx.x * 64;
  const int bj = blockIdx.y * 64;
  const int t = threadIdx.x;
  const int r = t >> 4;
  const int c4 = (t & 15) * 4;
#pragma unroll
  for (int it = 0; it < 4; ++it) {
    const int row = it * 16 + r;
    const f32x4 v = *(const f32x4*)(in + (size_t)(bj + row) * 1024 + bh + c4);
#pragma unroll
    for (int j = 0; j < 4; ++j) tile[c4 + j][row] = v[j];
  }
  __syncthreads();
#pragma unroll
  for (int it = 0; it < 4; ++it) {
    const int hrow = it * 16 + r;
    u16x4 oh, ol;
#pragma unroll
    for (int j = 0; j < 4; ++j) {
      const float f = tile[hrow][c4 + j];
      const u16 hv = f2bf(f);
      oh[j] = hv;
      ol[j] = f2bf(f - bf2f(hv));
    }
    *(u16x4*)(hi_o + (size_t)(bh + hrow) * 1024 + bj + c4) = oh;
    *(u16x4*)(lo_o + (size_t)(bh + hrow) * 1024 + bj + c4) = ol;
  }
}

// ---------------- 8-phase-style split-precision 3-pass GEMM ----------------
// C = (Ah+Al) @ (Bh+Bl)^T, acc = AhBh + AhBl + AlBh.  K=1024, lda=ldb=1024.
// 256x256 tile, BK=32, 8 waves (2x4), wave tile 128x64 (8x4 frags of 16x16x32).
// LDS 128 KiB: dbuf x {Ah,Al,Bh,Bl} x [256 rows][4 chunks of 8 u16].
// Chunk-swizzle: LDS(r,c) holds global chunk c^(r&3); applied on global source
// (gload_lds dest is linear) and on ds_read address (rule 21). 4 phases/K-tile:
// {ds_read frags | stage-issue next tile} barrier lgkm0 [24 MFMA] barrier.
// Boundary per K-tile: vmcnt(0) (stages issued >=2 phases early) + barrier.
// CMODE 0: qp (M=16384, split bf16 out). CMODE 1: scores (B=32 batches, f32 out).
template <int CMODE>
__global__ __launch_bounds__(512) void gemm3_8ph_k(
    const u16* __restrict__ Ah_, const u16* __restrict__ Al_,
    const u16* __restrict__ Bh_, const u16* __restrict__ Bl_,
    void* __restrict__ C0, void* __restrict__ C1) {
  __shared__ u16 lds[2][4][256 * 32];  // 131072 B
  const int bid = blockIdx.x;
  const int swz = (bid & 7) * 32 + (bid >> 3);  // bijective on 256; XCD-chunked
  int m0, n0;
  const u16 *Ah, *Al, *Bh, *Bl;
  float* Cf = nullptr;
  u16 *Chi = nullptr, *Clo = nullptr;
  if (CMODE == 0) {
    m0 = (swz >> 2) * 256;
    n0 = (swz & 3) * 256;
    Ah = Ah_; Al = Al_; Bh = Bh_; Bl = Bl_;
    Chi = (u16*)C0; Clo = (u16*)C1;
  } else {
    const int z = swz >> 3;               // 4 consecutive batches per XCD
    m0 = ((swz >> 2) & 1) * 256;
    n0 = (swz & 3) * 256;
    Ah = Ah_ + (size_t)z * 512 * 1024;  Al = Al_ + (size_t)z * 512 * 1024;
    Bh = Bh_ + (size_t)z * 1024 * 1024; Bl = Bl_ + (size_t)z * 1024 * 1024;
    Cf = (float*)C0 + (size_t)z * 512 * 1024;
  }
  const int tid = threadIdx.x;
  const int lane = tid & 63, wid = tid >> 6;
  const int wr = wid >> 2, wc = wid & 3;     // 2 x 4 waves
  const int sr = tid >> 2, sc = tid & 3;     // staging: row-in-half(0..127), dest chunk
  const int fr = lane & 15, fk = lane >> 4;  // frag row, k-chunk

  const u16* gm[4] = {Ah, Al, Bh, Bl};
  const int rbase[4] = {m0, m0, n0, n0};

  f32x4 acc[8][4] = {};

  // prologue: stage all 4 matrices of tile 0 into buf 0
#pragma unroll
  for (int q = 0; q < 4; ++q)
#pragma unroll
    for (int h = 0; h < 2; ++h) {
      const int r = h * 128 + sr;
      gload16(gm[q] + (size_t)(rbase[q] + r) * 1024 + ((sc ^ (r & 3)) * 8),
              &lds[0][q][h * 4096 + wid * 512]);
    }

  for (int t = 0; t < 32; ++t) {
    const int p = t & 1;
    // boundary: all waves' stages for buf[p] complete, then sync
    WAIT_VM0();
    BAR();
    short8 bh[4], bl[4];
#pragma unroll
    for (int q = 0; q < 4; ++q) {
      // ds_read this phase's A-frags (and all B-frags in phase 0)
      short8 ah0, ah1, al0, al1;
      {
        const int r0 = wr * 128 + (2 * q) * 16 + fr;
        const int r1 = r0 + 16;
        const int o0 = r0 * 32 + ((fk ^ (r0 & 3)) * 8);
        const int o1 = r1 * 32 + ((fk ^ (r1 & 3)) * 8);
        ah0 = *(const short8*)&lds[p][0][o0];
        al0 = *(const short8*)&lds[p][1][o0];
        ah1 = *(const short8*)&lds[p][0][o1];
        al1 = *(const short8*)&lds[p][1][o1];
      }
      if (q == 0) {
#pragma unroll
        for (int n = 0; n < 4; ++n) {
          const int rn = wc * 64 + n * 16 + fr;
          const int on = rn * 32 + ((fk ^ (rn & 3)) * 8);
          bh[n] = *(const short8*)&lds[p][2][on];
          bl[n] = *(const short8*)&lds[p][3][on];
        }
      }
      // front-loaded staging of tile t+1: phase 0 stages {Ah,Al}, phase 1 {Bh,Bl}
      if (t < 31 && q < 2) {
#pragma unroll
        for (int h = 0; h < 2; ++h) {
          const int mat0 = 2 * q;
          const int r = h * 128 + sr;
          gload16(gm[mat0] + (size_t)(rbase[mat0] + r) * 1024 + (t + 1) * 32 +
                      ((sc ^ (r & 3)) * 8),
                  &lds[p ^ 1][mat0][h * 4096 + wid * 512]);
          gload16(gm[mat0 + 1] + (size_t)(rbase[mat0 + 1] + r) * 1024 + (t + 1) * 32 +
                      ((sc ^ (r & 3)) * 8),
                  &lds[p ^ 1][mat0 + 1][h * 4096 + wid * 512]);
        }
      }
      BAR();
      WAIT_LGKM0();
      __builtin_amdgcn_sched_barrier(0);
      __builtin_amdgcn_s_setprio(1);
#pragma unroll
      for (int i = 0; i < 2; ++i) {
        const short8 a_h = i ? ah1 : ah0;
        const short8 a_l = i ? al1 : al0;
#pragma unroll
        for (int n = 0; n < 4; ++n) {
          acc[2 * q + i][n] =
              __builtin_amdgcn_mfma_f32_16x16x32_bf16(a_h, bh[n], acc[2 * q + i][n], 0, 0, 0);
          acc[2 * q + i][n] =
              __builtin_amdgcn_mfma_f32_16x16x32_bf16(a_h, bl[n], acc[2 * q + i][n], 0, 0, 0);
          acc[2 * q + i][n] =
              __builtin_amdgcn_mfma_f32_16x16x32_bf16(a_l, bh[n], acc[2 * q + i][n], 0, 0, 0);
        }
      }
      __builtin_amdgcn_s_setprio(0);
      BAR();
    }
  }

  const int cb = n0 + wc * 64 + fr;
  const int rb = m0 + wr * 128 + fk * 4;
  if (CMODE == 0) {
#pragma unroll
    for (int mf = 0; mf < 8; ++mf)
#pragma unroll
      for (int nf = 0; nf < 4; ++nf) {
        const int col = cb + nf * 16;
#pragma unroll
        for (int j = 0; j < 4; ++j) {
          const int row = rb + mf * 16 + j;
          const float kv = acc[mf][nf][j];
          const u16 hi = f2bf(kv);
          Chi[(size_t)row * 1024 + col] = hi;
          Clo[(size_t)row * 1024 + col] = f2bf(kv - bf2f(hi));
        }
      }
  } else {
#pragma unroll
    for (int mf = 0; mf < 8; ++mf)
#pragma unroll
      for (int nf = 0; nf < 4; ++nf) {
        const int col = cb + nf * 16;
#pragma unroll
        for (int j = 0; j < 4; ++j) {
          const int row = rb + mf * 16 + j;
          Cf[(size_t)row * 1024 + col] = acc[mf][nf][j];
        }
      }
  }
}

// ---------------- softmax over last dim (1024), writes compact bf16 attn ----------------
__global__ __launch_bounds__(256) void softmax_k(const float* __restrict__ S,
                                                 u16* __restrict__ Attn) {
  const float* rp = S + (size_t)blockIdx.x * 1024;
  const int tid = threadIdx.x;
  const int lane = tid & 63, wid = tid >> 6;
  const f32x4 v = ((const f32x4*)rp)[tid];
  float mx = fmaxf(fmaxf(v[0], v[1]), fmaxf(v[2], v[3]));
#pragma unroll
  for (int off = 32; off; off >>= 1) mx = fmaxf(mx, __shfl_xor(mx, off));
  __shared__ float red[4];
  __shared__ float red2[4];
  if (lane == 0) red[wid] = mx;
  __syncthreads();
  mx = fmaxf(fmaxf(red[0], red[1]), fmaxf(red[2], red[3]));
  const float e0 = __expf(v[0] - mx), e1 = __expf(v[1] - mx);
  const float e2 = __expf(v[2] - mx), e3 = __expf(v[3] - mx);
  float s = (e0 + e1) + (e2 + e3);
#pragma unroll
  for (int off = 32; off; off >>= 1) s += __shfl_xor(s, off);
  if (lane == 0) red2[wid] = s;
  __syncthreads();
  const float inv = 1.0f / (red2[0] + red2[1] + red2[2] + red2[3]);
  u16x4 o;
  o[0] = f2bf(e0 * inv); o[1] = f2bf(e1 * inv); o[2] = f2bf(e2 * inv); o[3] = f2bf(e3 * inv);
  ((u16x4*)(Attn + (size_t)blockIdx.x * 1024))[tid] = o;
}

// ---------------- ctx[b] = attn[b] @ hidden[b], bf16 out, XCD-swizzled ----------------
__global__ __launch_bounds__(256) void gemm_ctx_k(
    const u16* __restrict__ Attn, const u16* __restrict__ H, u16* __restrict__ Ctx) {
  const int wg = blockIdx.x;
  const int swz = (wg & 7) * 128 + (wg >> 3);
  const int z = swz >> 5;
  const int n0 = ((swz >> 2) & 7) * 128;
  const int m0 = (swz & 3) * 128;
  const u16* A = Attn + (size_t)z * 512 * 1024;
  const u16* B = H + (size_t)z * 1024 * 1024;

  __shared__ u16 As[128 * 32];
  __shared__ u16 Bs[128 * 64];  // [h 128][s 32 of 64], swizzled
  const int tid = threadIdx.x;
  const int lane = tid & 63, wid = tid >> 6;
  const int wr = wid >> 1, wc = wid & 1;

  f32x4 acc[4][4] = {};
  const int r_in = lane >> 2;
  const int c8 = (lane & 3) * 8;

  for (int kt = 0; kt < 32; ++kt) {
    const int k0 = kt * 32;
    __syncthreads();
#pragma unroll
    for (int i = 0; i < 2; ++i) {
      const int ch = wid + i * 4;
      const int row = ch * 16 + r_in;
      gload16(A + (size_t)(m0 + row) * 1024 + k0 + c8, &As[ch * 512]);
    }
#pragma unroll
    for (int i = 0; i < 2; ++i) {
      const int s = i * 16 + (tid >> 4);
      const int h0 = (tid & 15) * 8;
      union { u32x4 v; u16 u[8]; } r;
      r.v = *(const u32x4*)(B + (size_t)(k0 + s) * 1024 + n0 + h0);
#pragma unroll
      for (int j = 0; j < 8; ++j) {
        const int h = h0 + j;
        const int key = ((h >> 3) ^ h) & 7;
        Bs[h * 64 + (((s * 2) ^ (key << 4)) >> 1)] = r.u[j];
      }
    }
    __syncthreads();
    short8 af[4], bfr[4];
#pragma unroll
    for (int m = 0; m < 4; ++m)
      af[m] = *(const short8*)&As[(wr * 64 + m * 16 + (lane & 15)) * 32 + (lane >> 4) * 8];
#pragma unroll
    for (int n = 0; n < 4; ++n) {
      const int row = wc * 64 + n * 16 + (lane & 15);
      const int key = ((row >> 3) ^ row) & 7;
      const int boff = (((lane >> 4) * 16) ^ (key << 4)) >> 1;
      bfr[n] = *(const short8*)&Bs[row * 64 + boff];
    }
#pragma unroll
    for (int m = 0; m < 4; ++m)
#pragma unroll
      for (int n = 0; n < 4; ++n)
        acc[m][n] = __builtin_amdgcn_mfma_f32_16x16x32_bf16(af[m], bfr[n], acc[m][n], 0, 0, 0);
  }

  u16* C = Ctx + (size_t)z * 512 * 1024;
  const int cb = n0 + wc * 64 + (lane & 15);
  const int rb = m0 + wr * 64 + (lane >> 4) * 4;
#pragma unroll
  for (int n = 0; n < 4; ++n) {
    const int col = cb + n * 16;
#pragma unroll
    for (int m = 0; m < 4; ++m) {
      const int row = rb + m * 16;
#pragma unroll
      for (int j = 0; j < 4; ++j)
        C[(size_t)(row + j) * 1024 + col] = f2bf(acc[m][n][j]);
    }
  }
}

// ---------------- out = sigmoid(ctx @ V_w^T + V_b), f32 out ----------------
__global__ __launch_bounds__(256) void gemm_out_k(
    const u16* __restrict__ A, const u16* __restrict__ Bt,
    const float* __restrict__ bias, float* __restrict__ C) {
  __shared__ u16 As[128 * 32];
  __shared__ u16 Bs[128 * 32];
  const int tid = threadIdx.x;
  const int lane = tid & 63, wid = tid >> 6;
  const int wr = wid >> 1, wc = wid & 1;
  const int m0 = blockIdx.x * 128;
  const int n0 = blockIdx.y * 128;

  f32x4 acc[4][4] = {};
  const int r_in = lane >> 2;
  const int c8 = (lane & 3) * 8;

  for (int kt = 0; kt < 32; ++kt) {
    const int k0 = kt * 32;
    __syncthreads();
#pragma unroll
    for (int i = 0; i < 2; ++i) {
      const int ch = wid + i * 4;
      const int row = ch * 16 + r_in;
      gload16(A + (size_t)(m0 + row) * 1024 + k0 + c8, &As[ch * 512]);
      gload16(Bt + (size_t)(n0 + row) * 1024 + k0 + c8, &Bs[ch * 512]);
    }
    __syncthreads();
    short8 af[4], bfr[4];
#pragma unroll
    for (int m = 0; m < 4; ++m)
      af[m] = *(const short8*)&As[(wr * 64 + m * 16 + (lane & 15)) * 32 + (lane >> 4) * 8];
#pragma unroll
    for (int n = 0; n < 4; ++n)
      bfr[n] = *(const short8*)&Bs[(wc * 64 + n * 16 + (lane & 15)) * 32 + (lane >> 4) * 8];
#pragma unroll
    for (int m = 0; m < 4; ++m)
#pragma unroll
      for (int n = 0; n < 4; ++n)
        acc[m][n] = __builtin_amdgcn_mfma_f32_16x16x32_bf16(af[m], bfr[n], acc[m][n], 0, 0, 0);
  }

  const int cb = n0 + wc * 64 + (lane & 15);
  const int rb = m0 + wr * 64 + (lane >> 4) * 4;
#pragma unroll
  for (int n = 0; n < 4; ++n) {
    const int col = cb + n * 16;
    const float bv = bias[col];
#pragma unroll
    for (int m = 0; m < 4; ++m) {
      const int row = rb + m * 16;
#pragma unroll
      for (int j = 0; j < 4; ++j) {
        const float x = acc[m][n][j] + bv;
        C[(size_t)(row + j) * 1024 + col] = 1.0f / (1.0f + __expf(-x));
      }
    }
  }
}

// ---------------- launch ----------------
// Shapes: S=1024, B=32, H=1024, T=512.
//   q'  = x @ K_w                      (split 3-pass, 8-phase; K_b dropped)
//   scr = q'[b] @ hidden[b]^T          (split 3-pass, 8-phase, f32)
//   attn = softmax(scr)                (compact bf16 [B,T,S])
//   ctx = attn[b] @ hidden[b]          (bf16, swizzled transpose-staging)
//   out = sigmoid(ctx @ V_w^T + V_b)   (f32)
// ws layout (MB): hhi 0-64 | hlo 64-128 | qhi 128-160 | qlo 160-192 |
//   scores f32 192-256 | attn bf16 256-288 | ctx bf16 288-320 | weights 320-326
extern "C" void kernel_launch(void* const* d_in, const int* in_sizes, int n_in,
                              void* d_out, int out_size, void* d_ws, size_t ws_size,
                              hipStream_t stream) {
  const float* hidden = (const float*)d_in[0];
  const float* x = (const float*)d_in[1];
  // d_in[2] problem_q unused; d_in[4] K_b dropped (softmax shift invariance)
  const float* K_w = (const float*)d_in[3];
  const float* V_w = (const float*)d_in[5];
  const float* V_b = (const float*)d_in[6];

  char* ws = (char*)d_ws;
  u16* hhi = (u16*)(ws);
  u16* hlo = (u16*)(ws + 67108864);
  u16* qhi = (u16*)(ws + 134217728);
  u16* qlo = (u16*)(ws + 167772160);
  float* scoresF = (float*)(ws + 201326592);
  u16* attn = (u16*)(ws + 268435456);
  u16* ctx = (u16*)(ws + 301989888);
  u16* kwt_h = (u16*)(ws + 335544320);
  u16* kwt_l = kwt_h + 1024 * 1024;
  u16* vw = kwt_h + 2 * 1024 * 1024;
  u16* xhi = (u16*)d_out;
  u16* xlo = xhi + 32L * 512 * 1024;
  float* out = (float*)d_out;

  // 1. hidden [S,B,H] -> split bf16 [B,S,H]
  cvt_hidden_split_k<<<dim3(1024, 32), 256, 0, stream>>>(hidden, hhi, hlo);
  // 2. x -> split bf16 (into d_out; dead before final GEMM overwrites it)
  cvt_split_k<<<2048, 256, 0, stream>>>(x, xhi, xlo, 32L * 512 * 1024 / 4);
  // 3. weights: K_w transposed split, V_w single
  cvt_w_split_t_k<<<dim3(16, 16), 256, 0, stream>>>(K_w, kwt_h, kwt_l);
  cvt_f32_bf16_k<<<1024, 256, 0, stream>>>(V_w, vw, 1024L * 1024 / 4);
  // 4. q' = x @ K_w  (split 3-pass, 8-phase 256^2)
  gemm3_8ph_k<0><<<256, 512, 0, stream>>>(xhi, xlo, kwt_h, kwt_l, qhi, qlo);
  // 5. scores[b] = q'[b] @ hidden[b]^T  (split 3-pass, 8-phase 256^2, f32 out)
  gemm3_8ph_k<1><<<256, 512, 0, stream>>>(qhi, qlo, hhi, hlo, scoresF, nullptr);
  // 6. softmax over S -> compact bf16 attn
  softmax_k<<<16384, 256, 0, stream>>>(scoresF, attn);
  // 7. ctx[b] = attn[b] @ hidden[b]  (bf16, XCD-swizzled, conflict-fixed staging)
  gemm_ctx_k<<<1024, 256, 0, stream>>>(attn, hhi, ctx);
  // 8. out = sigmoid(ctx @ V_w^T + V_b)
  gemm_out_k<<<dim3(128, 8), 256, 0, stream>>>(ctx, vw, V_b, out);
}

// Round 6
// 383.787 us; speedup vs baseline: 1.9835x; 1.1561x over previous
//
#include <hip/hip_runtime.h>

typedef unsigned short u16;
typedef __attribute__((ext_vector_type(8))) short short8;
typedef __attribute__((ext_vector_type(4))) float f32x4;
typedef __attribute__((ext_vector_type(4))) u16 u16x4;
typedef __attribute__((ext_vector_type(4))) unsigned int u32x4;

#define DEVINL static __device__ __forceinline__

DEVINL u16 f2bf(float f) {
  unsigned u = __builtin_bit_cast(unsigned, f);
  u += 0x7fffu + ((u >> 16) & 1u);
  return (u16)(u >> 16);
}
DEVINL float bf2f(u16 h) {
  return __builtin_bit_cast(float, ((unsigned)h) << 16);
}

// async global->LDS, 16B per lane; lds base must be wave-uniform
DEVINL void gload16(const void* g, void* l) {
  __builtin_amdgcn_global_load_lds(
      (const __attribute__((address_space(1))) void*)g,
      (__attribute__((address_space(3))) void*)l, 16, 0, 0);
}

#define BAR() asm volatile("s_barrier" ::: "memory")
#define WAIT_VM0() asm volatile("s_waitcnt vmcnt(0)" ::: "memory")
#define WAIT_LGKM0() asm volatile("s_waitcnt lgkmcnt(0)" ::: "memory")

// ---------------- converts ----------------

// hidden [S=1024, B=32, H=1024] f32 -> hhi/hlo [B,S,H] split bf16 + hT [B,H,S] bf16 (hi)
// grid (16 s-tiles, 16 h-tiles, 32 b), 256 thr. 64x64 tile, LDS transpose for hT.
__global__ __launch_bounds__(256) void cvt_hidden3_k(const float* __restrict__ hid,
                                                     u16* __restrict__ hhi,
                                                     u16* __restrict__ hlo,
                                                     u16* __restrict__ hT) {
  __shared__ u16 tl[64][72];
  const int s0 = blockIdx.x * 64;
  const int h0 = blockIdx.y * 64;
  const int b = blockIdx.z;
  const int t = threadIdx.x;
  const int r = t >> 4;
  const int c4 = (t & 15) * 4;
#pragma unroll
  for (int it = 0; it < 4; ++it) {
    const int s = it * 16 + r;
    const f32x4 v = *(const f32x4*)(hid + ((size_t)(s0 + s) * 32 + b) * 1024 + h0 + c4);
    u16x4 oh, ol;
#pragma unroll
    for (int j = 0; j < 4; ++j) {
      const u16 hv = f2bf(v[j]);
      oh[j] = hv;
      ol[j] = f2bf(v[j] - bf2f(hv));
      tl[s][c4 + j] = hv;
    }
    const size_t base = ((size_t)b * 1024 + s0 + s) * 1024 + h0 + c4;
    *(u16x4*)(hhi + base) = oh;
    *(u16x4*)(hlo + base) = ol;
  }
  __syncthreads();
  const int h = t >> 2;
  const int sq = (t & 3) * 16;
  u16 tmp[16] __attribute__((aligned(16)));
#pragma unroll
  for (int i = 0; i < 16; ++i) tmp[i] = tl[sq + i][h];
  u16* dst = hT + ((size_t)b * 1024 + h0 + h) * 1024 + s0 + sq;
  *(u32x4*)(dst) = *(const u32x4*)&tmp[0];
  *(u32x4*)(dst + 8) = *(const u32x4*)&tmp[8];
}

// generic f32 -> split bf16 (hi, lo)
__global__ __launch_bounds__(256) void cvt_split_k(const float* __restrict__ in,
                                                   u16* __restrict__ hi_o,
                                                   u16* __restrict__ lo_o, long n4) {
  long i = (long)blockIdx.x * 256 + threadIdx.x;
  const long stride = (long)gridDim.x * 256;
  for (; i < n4; i += stride) {
    const f32x4 v = ((const f32x4*)in)[i];
    u16x4 oh, ol;
#pragma unroll
    for (int j = 0; j < 4; ++j) {
      const u16 hi = f2bf(v[j]);
      oh[j] = hi;
      ol[j] = f2bf(v[j] - bf2f(hi));
    }
    ((u16x4*)hi_o)[i] = oh;
    ((u16x4*)lo_o)[i] = ol;
  }
}

// generic f32 -> bf16 (single)
__global__ __launch_bounds__(256) void cvt_f32_bf16_k(const float* __restrict__ in,
                                                      u16* __restrict__ out, long n4) {
  long i = (long)blockIdx.x * 256 + threadIdx.x;
  const long stride = (long)gridDim.x * 256;
  for (; i < n4; i += stride) {
    const f32x4 v = ((const f32x4*)in)[i];
    u16x4 o;
#pragma unroll
    for (int j = 0; j < 4; ++j) o[j] = f2bf(v[j]);
    ((u16x4*)out)[i] = o;
  }
}

// K_w [j=1024][h=1024] f32 -> transposed split bf16: out[h][j]
__global__ __launch_bounds__(256) void cvt_w_split_t_k(const float* __restrict__ in,
                                                       u16* __restrict__ hi_o,
                                                       u16* __restrict__ lo_o) {
  __shared__ float tile[64][65];
  const int bh = blockIdx.x * 64;
  const int bj = blockIdx.y * 64;
  const int t = threadIdx.x;
  const int r = t >> 4;
  const int c4 = (t & 15) * 4;
#pragma unroll
  for (int it = 0; it < 4; ++it) {
    const int row = it * 16 + r;
    const f32x4 v = *(const f32x4*)(in + (size_t)(bj + row) * 1024 + bh + c4);
#pragma unroll
    for (int j = 0; j < 4; ++j) tile[c4 + j][row] = v[j];
  }
  __syncthreads();
#pragma unroll
  for (int it = 0; it < 4; ++it) {
    const int hrow = it * 16 + r;
    u16x4 oh, ol;
#pragma unroll
    for (int j = 0; j < 4; ++j) {
      const float f = tile[hrow][c4 + j];
      const u16 hv = f2bf(f);
      oh[j] = hv;
      ol[j] = f2bf(f - bf2f(hv));
    }
    *(u16x4*)(hi_o + (size_t)(bh + hrow) * 1024 + bj + c4) = oh;
    *(u16x4*)(lo_o + (size_t)(bh + hrow) * 1024 + bj + c4) = ol;
  }
}

// ---------------- 8-phase-style split-precision 3-pass GEMM ----------------
// C = (Ah+Al) @ (Bh+Bl)^T, acc = AhBh + AhBl + AlBh.  K=1024, lda=ldb=1024.
// 256x256 tile, BK=32, 8 waves (2x4), wave tile 128x64.
// CMODE 0: qp (M=16384, split bf16 out). CMODE 1: scores (B=32 batches, f32 out).
template <int CMODE>
__global__ __launch_bounds__(512) void gemm3_8ph_k(
    const u16* __restrict__ Ah_, const u16* __restrict__ Al_,
    const u16* __restrict__ Bh_, const u16* __restrict__ Bl_,
    void* __restrict__ C0, void* __restrict__ C1) {
  __shared__ u16 lds[2][4][256 * 32];  // 131072 B
  const int bid = blockIdx.x;
  const int swz = (bid & 7) * 32 + (bid >> 3);  // bijective on 256; XCD-chunked
  int m0, n0;
  const u16 *Ah, *Al, *Bh, *Bl;
  float* Cf = nullptr;
  u16 *Chi = nullptr, *Clo = nullptr;
  if (CMODE == 0) {
    m0 = (swz >> 2) * 256;
    n0 = (swz & 3) * 256;
    Ah = Ah_; Al = Al_; Bh = Bh_; Bl = Bl_;
    Chi = (u16*)C0; Clo = (u16*)C1;
  } else {
    const int z = swz >> 3;               // 4 consecutive batches per XCD
    m0 = ((swz >> 2) & 1) * 256;
    n0 = (swz & 3) * 256;
    Ah = Ah_ + (size_t)z * 512 * 1024;  Al = Al_ + (size_t)z * 512 * 1024;
    Bh = Bh_ + (size_t)z * 1024 * 1024; Bl = Bl_ + (size_t)z * 1024 * 1024;
    Cf = (float*)C0 + (size_t)z * 512 * 1024;
  }
  const int tid = threadIdx.x;
  const int lane = tid & 63, wid = tid >> 6;
  const int wr = wid >> 2, wc = wid & 3;     // 2 x 4 waves
  const int sr = tid >> 2, sc = tid & 3;     // staging: row-in-half(0..127), dest chunk
  const int fr = lane & 15, fk = lane >> 4;  // frag row, k-chunk

  const u16* gm[4] = {Ah, Al, Bh, Bl};
  const int rbase[4] = {m0, m0, n0, n0};

  f32x4 acc[8][4] = {};

  // prologue: stage all 4 matrices of tile 0 into buf 0
#pragma unroll
  for (int q = 0; q < 4; ++q)
#pragma unroll
    for (int h = 0; h < 2; ++h) {
      const int r = h * 128 + sr;
      gload16(gm[q] + (size_t)(rbase[q] + r) * 1024 + ((sc ^ (r & 3)) * 8),
              &lds[0][q][h * 4096 + wid * 512]);
    }

  for (int t = 0; t < 32; ++t) {
    const int p = t & 1;
    WAIT_VM0();
    BAR();
    short8 bh[4], bl[4];
#pragma unroll
    for (int q = 0; q < 4; ++q) {
      short8 ah0, ah1, al0, al1;
      {
        const int r0 = wr * 128 + (2 * q) * 16 + fr;
        const int r1 = r0 + 16;
        const int o0 = r0 * 32 + ((fk ^ (r0 & 3)) * 8);
        const int o1 = r1 * 32 + ((fk ^ (r1 & 3)) * 8);
        ah0 = *(const short8*)&lds[p][0][o0];
        al0 = *(const short8*)&lds[p][1][o0];
        ah1 = *(const short8*)&lds[p][0][o1];
        al1 = *(const short8*)&lds[p][1][o1];
      }
      if (q == 0) {
#pragma unroll
        for (int n = 0; n < 4; ++n) {
          const int rn = wc * 64 + n * 16 + fr;
          const int on = rn * 32 + ((fk ^ (rn & 3)) * 8);
          bh[n] = *(const short8*)&lds[p][2][on];
          bl[n] = *(const short8*)&lds[p][3][on];
        }
      }
      if (t < 31 && q < 2) {
#pragma unroll
        for (int h = 0; h < 2; ++h) {
          const int mat0 = 2 * q;
          const int r = h * 128 + sr;
          gload16(gm[mat0] + (size_t)(rbase[mat0] + r) * 1024 + (t + 1) * 32 +
                      ((sc ^ (r & 3)) * 8),
                  &lds[p ^ 1][mat0][h * 4096 + wid * 512]);
          gload16(gm[mat0 + 1] + (size_t)(rbase[mat0 + 1] + r) * 1024 + (t + 1) * 32 +
                      ((sc ^ (r & 3)) * 8),
                  &lds[p ^ 1][mat0 + 1][h * 4096 + wid * 512]);
        }
      }
      BAR();
      WAIT_LGKM0();
      __builtin_amdgcn_sched_barrier(0);
      __builtin_amdgcn_s_setprio(1);
#pragma unroll
      for (int i = 0; i < 2; ++i) {
        const short8 a_h = i ? ah1 : ah0;
        const short8 a_l = i ? al1 : al0;
#pragma unroll
        for (int n = 0; n < 4; ++n) {
          acc[2 * q + i][n] =
              __builtin_amdgcn_mfma_f32_16x16x32_bf16(a_h, bh[n], acc[2 * q + i][n], 0, 0, 0);
          acc[2 * q + i][n] =
              __builtin_amdgcn_mfma_f32_16x16x32_bf16(a_h, bl[n], acc[2 * q + i][n], 0, 0, 0);
          acc[2 * q + i][n] =
              __builtin_amdgcn_mfma_f32_16x16x32_bf16(a_l, bh[n], acc[2 * q + i][n], 0, 0, 0);
        }
      }
      __builtin_amdgcn_s_setprio(0);
      BAR();
    }
  }

  const int cb = n0 + wc * 64 + fr;
  const int rb = m0 + wr * 128 + fk * 4;
  if (CMODE == 0) {
#pragma unroll
    for (int mf = 0; mf < 8; ++mf)
#pragma unroll
      for (int nf = 0; nf < 4; ++nf) {
        const int col = cb + nf * 16;
#pragma unroll
        for (int j = 0; j < 4; ++j) {
          const int row = rb + mf * 16 + j;
          const float kv = acc[mf][nf][j];
          const u16 hi = f2bf(kv);
          Chi[(size_t)row * 1024 + col] = hi;
          Clo[(size_t)row * 1024 + col] = f2bf(kv - bf2f(hi));
        }
      }
  } else {
#pragma unroll
    for (int mf = 0; mf < 8; ++mf)
#pragma unroll
      for (int nf = 0; nf < 4; ++nf) {
        const int col = cb + nf * 16;
#pragma unroll
        for (int j = 0; j < 4; ++j) {
          const int row = rb + mf * 16 + j;
          Cf[(size_t)row * 1024 + col] = acc[mf][nf][j];
        }
      }
  }
}

// ---------------- single-pass 8-phase GEMM: C = A @ Bt^T ----------------
// 256x256 tile, BK=64, 8 waves (2x4), wave tile 128x64, 4 phases/K-tile.
// LDS 128 KiB: dbuf x {A,Bt} x [256 rows][8 chunks of 8 u16] (128-B pitch).
// Chunk swizzle g = c ^ (r&7): frag reads hit 8 banks (2-way, free).
// CM 0: ctx = attn[b] @ hT[b]^T, batched, bf16 out.
// CM 1: out = sigmoid(A @ Bt^T + bias), flat M=16384, f32 out.
template <int CM>
__global__ __launch_bounds__(512) void gemm1_8ph_k(
    const u16* __restrict__ A_, const u16* __restrict__ Bt_,
    const float* __restrict__ bias, void* __restrict__ Cout) {
  __shared__ u16 lds[2][2][256 * 64];  // 131072 B
  const int bid = blockIdx.x;
  const int swz = (bid & 7) * 32 + (bid >> 3);
  int m0, n0;
  const u16 *A, *Bt;
  float* Cf = nullptr;
  u16* Cb = nullptr;
  if (CM == 0) {
    const int z = swz >> 3;
    m0 = ((swz >> 2) & 1) * 256;
    n0 = (swz & 3) * 256;
    A = A_ + (size_t)z * 512 * 1024;
    Bt = Bt_ + (size_t)z * 1024 * 1024;
    Cb = (u16*)Cout + (size_t)z * 512 * 1024;
  } else {
    m0 = (swz >> 2) * 256;
    n0 = (swz & 3) * 256;
    A = A_; Bt = Bt_;
    Cf = (float*)Cout;
  }
  const int tid = threadIdx.x;
  const int lane = tid & 63, wid = tid >> 6;
  const int wr = wid >> 2, wc = wid & 3;
  const int fr = lane & 15, fk = lane >> 4;

  f32x4 acc[8][4] = {};

  // stage one mat's K-tile: 2048 slots of 16B, 4 per thread
#define STAGE1(pb, q, gp, rb, kt)                                              \
  {                                                                            \
    _Pragma("unroll") for (int j = 0; j < 4; ++j) {                            \
      const int slot = j * 512 + tid;                                          \
      const int r = slot >> 3;                                                 \
      const int g = (slot & 7) ^ (r & 7);                                      \
      gload16((gp) + (size_t)((rb) + r) * 1024 + (kt) * 64 + g * 8,            \
              &lds[pb][q][(j * 512 + wid * 64) * 8]);                          \
    }                                                                          \
  }

  // prologue: tile 0 into buf 0
  STAGE1(0, 0, A, m0, 0);
  STAGE1(0, 1, Bt, n0, 0);

  for (int t = 0; t < 16; ++t) {
    const int p = t & 1;
    WAIT_VM0();
    BAR();
    short8 bfr[4][2];
#pragma unroll
    for (int ph = 0; ph < 4; ++ph) {
      short8 a[2][2];
#pragma unroll
      for (int i = 0; i < 2; ++i) {
        const int r = wr * 128 + (ph * 2 + i) * 16 + fr;
#pragma unroll
        for (int ks = 0; ks < 2; ++ks) {
          const int g = (ks * 4 + fk) ^ (r & 7);
          a[i][ks] = *(const short8*)&lds[p][0][r * 64 + g * 8];
        }
      }
      if (ph == 0) {
#pragma unroll
        for (int nf = 0; nf < 4; ++nf) {
          const int rn = wc * 64 + nf * 16 + fr;
#pragma unroll
          for (int ks = 0; ks < 2; ++ks) {
            const int g = (ks * 4 + fk) ^ (rn & 7);
            bfr[nf][ks] = *(const short8*)&lds[p][1][rn * 64 + g * 8];
          }
        }
        if (t < 15) {
          STAGE1(p ^ 1, 0, A, m0, t + 1);
          STAGE1(p ^ 1, 1, Bt, n0, t + 1);
        }
      }
      BAR();
      WAIT_LGKM0();
      __builtin_amdgcn_sched_barrier(0);
      __builtin_amdgcn_s_setprio(1);
#pragma unroll
      for (int i = 0; i < 2; ++i)
#pragma unroll
        for (int nf = 0; nf < 4; ++nf) {
          acc[ph * 2 + i][nf] = __builtin_amdgcn_mfma_f32_16x16x32_bf16(
              a[i][0], bfr[nf][0], acc[ph * 2 + i][nf], 0, 0, 0);
          acc[ph * 2 + i][nf] = __builtin_amdgcn_mfma_f32_16x16x32_bf16(
              a[i][1], bfr[nf][1], acc[ph * 2 + i][nf], 0, 0, 0);
        }
      __builtin_amdgcn_s_setprio(0);
      BAR();
    }
  }
#undef STAGE1

  const int cb = n0 + wc * 64 + fr;
  const int rb = m0 + wr * 128 + fk * 4;
  if (CM == 0) {
#pragma unroll
    for (int mf = 0; mf < 8; ++mf)
#pragma unroll
      for (int nf = 0; nf < 4; ++nf) {
        const int col = cb + nf * 16;
#pragma unroll
        for (int j = 0; j < 4; ++j) {
          const int row = rb + mf * 16 + j;
          Cb[(size_t)row * 1024 + col] = f2bf(acc[mf][nf][j]);
        }
      }
  } else {
#pragma unroll
    for (int mf = 0; mf < 8; ++mf)
#pragma unroll
      for (int nf = 0; nf < 4; ++nf) {
        const int col = cb + nf * 16;
        const float bv = bias[col];
#pragma unroll
        for (int j = 0; j < 4; ++j) {
          const int row = rb + mf * 16 + j;
          const float xv = acc[mf][nf][j] + bv;
          Cf[(size_t)row * 1024 + col] = 1.0f / (1.0f + __expf(-xv));
        }
      }
  }
}

// ---------------- softmax over last dim (1024), writes compact bf16 attn ----------------
__global__ __launch_bounds__(256) void softmax_k(const float* __restrict__ S,
                                                 u16* __restrict__ Attn) {
  const float* rp = S + (size_t)blockIdx.x * 1024;
  const int tid = threadIdx.x;
  const int lane = tid & 63, wid = tid >> 6;
  const f32x4 v = ((const f32x4*)rp)[tid];
  float mx = fmaxf(fmaxf(v[0], v[1]), fmaxf(v[2], v[3]));
#pragma unroll
  for (int off = 32; off; off >>= 1) mx = fmaxf(mx, __shfl_xor(mx, off));
  __shared__ float red[4];
  __shared__ float red2[4];
  if (lane == 0) red[wid] = mx;
  __syncthreads();
  mx = fmaxf(fmaxf(red[0], red[1]), fmaxf(red[2], red[3]));
  const float e0 = __expf(v[0] - mx), e1 = __expf(v[1] - mx);
  const float e2 = __expf(v[2] - mx), e3 = __expf(v[3] - mx);
  float s = (e0 + e1) + (e2 + e3);
#pragma unroll
  for (int off = 32; off; off >>= 1) s += __shfl_xor(s, off);
  if (lane == 0) red2[wid] = s;
  __syncthreads();
  const float inv = 1.0f / (red2[0] + red2[1] + red2[2] + red2[3]);
  u16x4 o;
  o[0] = f2bf(e0 * inv); o[1] = f2bf(e1 * inv); o[2] = f2bf(e2 * inv); o[3] = f2bf(e3 * inv);
  ((u16x4*)(Attn + (size_t)blockIdx.x * 1024))[tid] = o;
}

// ---------------- launch ----------------
// Shapes: S=1024, B=32, H=1024, T=512.
//   q'  = x @ K_w                      (split 3-pass, 8-phase; K_b dropped)
//   scr = q'[b] @ hidden[b]^T          (split 3-pass, 8-phase, f32)
//   attn = softmax(scr)                (compact bf16 [B,T,S])
//   ctx = attn[b] @ hT[b]^T            (single-pass 8-phase, bf16)
//   out = sigmoid(ctx @ V_w^T + V_b)   (single-pass 8-phase, f32)
// ws (MB): hhi 0-64 (→ctx 0-32) | hlo 64-128 | hT 128-192 |
//   qhi 192-224, qlo 224-256 (→attn 192-224) | scores f32 256-320 | weights 320-326
extern "C" void kernel_launch(void* const* d_in, const int* in_sizes, int n_in,
                              void* d_out, int out_size, void* d_ws, size_t ws_size,
                              hipStream_t stream) {
  const float* hidden = (const float*)d_in[0];
  const float* x = (const float*)d_in[1];
  // d_in[2] problem_q unused; d_in[4] K_b dropped (softmax shift invariance)
  const float* K_w = (const float*)d_in[3];
  const float* V_w = (const float*)d_in[5];
  const float* V_b = (const float*)d_in[6];

  char* ws = (char*)d_ws;
  u16* hhi = (u16*)(ws);
  u16* hlo = (u16*)(ws + 67108864);
  u16* hT  = (u16*)(ws + 134217728);
  u16* qhi = (u16*)(ws + 201326592);
  u16* qlo = (u16*)(ws + 234881024);
  float* scoresF = (float*)(ws + 268435456);
  u16* attn = qhi;          // reuse (q' dead after scores)
  u16* ctx = hhi;           // reuse (hhi dead after scores)
  u16* kwt_h = (u16*)(ws + 335544320);
  u16* kwt_l = kwt_h + 1024 * 1024;
  u16* vw = kwt_h + 2 * 1024 * 1024;
  u16* xhi = (u16*)d_out;
  u16* xlo = xhi + 32L * 512 * 1024;
  float* out = (float*)d_out;

  // 1. hidden [S,B,H] -> split bf16 [B,S,H] + transposed hi [B,H,S]
  cvt_hidden3_k<<<dim3(16, 16, 32), 256, 0, stream>>>(hidden, hhi, hlo, hT);
  // 2. x -> split bf16 (into d_out; dead before final GEMM overwrites it)
  cvt_split_k<<<2048, 256, 0, stream>>>(x, xhi, xlo, 32L * 512 * 1024 / 4);
  // 3. weights: K_w transposed split, V_w single
  cvt_w_split_t_k<<<dim3(16, 16), 256, 0, stream>>>(K_w, kwt_h, kwt_l);
  cvt_f32_bf16_k<<<1024, 256, 0, stream>>>(V_w, vw, 1024L * 1024 / 4);
  // 4. q' = x @ K_w  (split 3-pass, 8-phase 256^2)
  gemm3_8ph_k<0><<<256, 512, 0, stream>>>(xhi, xlo, kwt_h, kwt_l, qhi, qlo);
  // 5. scores[b] = q'[b] @ hidden[b]^T  (split 3-pass, 8-phase 256^2, f32 out)
  gemm3_8ph_k<1><<<256, 512, 0, stream>>>(qhi, qlo, hhi, hlo, scoresF, nullptr);
  // 6. softmax over S -> compact bf16 attn
  softmax_k<<<16384, 256, 0, stream>>>(scoresF, attn);
  // 7. ctx[b] = attn[b] @ hT[b]^T  (single-pass 8-phase)
  gemm1_8ph_k<0><<<256, 512, 0, stream>>>(attn, hT, nullptr, ctx);
  // 8. out = sigmoid(ctx @ V_w^T + V_b)  (single-pass 8-phase)
  gemm1_8ph_k<1><<<256, 512, 0, stream>>>(ctx, vw, V_b, out);
}

// Round 7
// 378.519 us; speedup vs baseline: 2.0111x; 1.0139x over previous
//
#include <hip/hip_runtime.h>

typedef unsigned short u16;
typedef __attribute__((ext_vector_type(8))) short short8;
typedef __attribute__((ext_vector_type(4))) float f32x4;
typedef __attribute__((ext_vector_type(4))) u16 u16x4;
typedef __attribute__((ext_vector_type(4))) unsigned int u32x4;

#define DEVINL static __device__ __forceinline__

DEVINL u16 f2bf(float f) {
  unsigned u = __builtin_bit_cast(unsigned, f);
  u += 0x7fffu + ((u >> 16) & 1u);
  return (u16)(u >> 16);
}
DEVINL float bf2f(u16 h) {
  return __builtin_bit_cast(float, ((unsigned)h) << 16);
}

// async global->LDS, 16B per lane; lds base must be wave-uniform
DEVINL void gload16(const void* g, void* l) {
  __builtin_amdgcn_global_load_lds(
      (const __attribute__((address_space(1))) void*)g,
      (__attribute__((address_space(3))) void*)l, 16, 0, 0);
}

#define BAR() asm volatile("s_barrier" ::: "memory")
#define WAIT_VM0() asm volatile("s_waitcnt vmcnt(0)" ::: "memory")
#define WAIT_LGKM0() asm volatile("s_waitcnt lgkmcnt(0)" ::: "memory")

// ---------------- converts ----------------

// hidden [S=1024, B=32, H=1024] f32 -> hhi/hlo [B,S,H] split bf16 + hT [B,H,S] bf16 (hi)
__global__ __launch_bounds__(256) void cvt_hidden3_k(const float* __restrict__ hid,
                                                     u16* __restrict__ hhi,
                                                     u16* __restrict__ hlo,
                                                     u16* __restrict__ hT) {
  __shared__ u16 tl[64][72];
  const int s0 = blockIdx.x * 64;
  const int h0 = blockIdx.y * 64;
  const int b = blockIdx.z;
  const int t = threadIdx.x;
  const int r = t >> 4;
  const int c4 = (t & 15) * 4;
#pragma unroll
  for (int it = 0; it < 4; ++it) {
    const int s = it * 16 + r;
    const f32x4 v = *(const f32x4*)(hid + ((size_t)(s0 + s) * 32 + b) * 1024 + h0 + c4);
    u16x4 oh, ol;
#pragma unroll
    for (int j = 0; j < 4; ++j) {
      const u16 hv = f2bf(v[j]);
      oh[j] = hv;
      ol[j] = f2bf(v[j] - bf2f(hv));
      tl[s][c4 + j] = hv;
    }
    const size_t base = ((size_t)b * 1024 + s0 + s) * 1024 + h0 + c4;
    *(u16x4*)(hhi + base) = oh;
    *(u16x4*)(hlo + base) = ol;
  }
  __syncthreads();
  const int h = t >> 2;
  const int sq = (t & 3) * 16;
  u16 tmp[16] __attribute__((aligned(16)));
#pragma unroll
  for (int i = 0; i < 16; ++i) tmp[i] = tl[sq + i][h];
  u16* dst = hT + ((size_t)b * 1024 + h0 + h) * 1024 + s0 + sq;
  *(u32x4*)(dst) = *(const u32x4*)&tmp[0];
  *(u32x4*)(dst + 8) = *(const u32x4*)&tmp[8];
}

// generic f32 -> split bf16 (hi, lo)
__global__ __launch_bounds__(256) void cvt_split_k(const float* __restrict__ in,
                                                   u16* __restrict__ hi_o,
                                                   u16* __restrict__ lo_o, long n4) {
  long i = (long)blockIdx.x * 256 + threadIdx.x;
  const long stride = (long)gridDim.x * 256;
  for (; i < n4; i += stride) {
    const f32x4 v = ((const f32x4*)in)[i];
    u16x4 oh, ol;
#pragma unroll
    for (int j = 0; j < 4; ++j) {
      const u16 hi = f2bf(v[j]);
      oh[j] = hi;
      ol[j] = f2bf(v[j] - bf2f(hi));
    }
    ((u16x4*)hi_o)[i] = oh;
    ((u16x4*)lo_o)[i] = ol;
  }
}

// generic f32 -> bf16 (single)
__global__ __launch_bounds__(256) void cvt_f32_bf16_k(const float* __restrict__ in,
                                                      u16* __restrict__ out, long n4) {
  long i = (long)blockIdx.x * 256 + threadIdx.x;
  const long stride = (long)gridDim.x * 256;
  for (; i < n4; i += stride) {
    const f32x4 v = ((const f32x4*)in)[i];
    u16x4 o;
#pragma unroll
    for (int j = 0; j < 4; ++j) o[j] = f2bf(v[j]);
    ((u16x4*)out)[i] = o;
  }
}

// K_w [j=1024][h=1024] f32 -> transposed split bf16: out[h][j]
__global__ __launch_bounds__(256) void cvt_w_split_t_k(const float* __restrict__ in,
                                                       u16* __restrict__ hi_o,
                                                       u16* __restrict__ lo_o) {
  __shared__ float tile[64][65];
  const int bh = blockIdx.x * 64;
  const int bj = blockIdx.y * 64;
  const int t = threadIdx.x;
  const int r = t >> 4;
  const int c4 = (t & 15) * 4;
#pragma unroll
  for (int it = 0; it < 4; ++it) {
    const int row = it * 16 + r;
    const f32x4 v = *(const f32x4*)(in + (size_t)(bj + row) * 1024 + bh + c4);
#pragma unroll
    for (int j = 0; j < 4; ++j) tile[c4 + j][row] = v[j];
  }
  __syncthreads();
#pragma unroll
  for (int it = 0; it < 4; ++it) {
    const int hrow = it * 16 + r;
    u16x4 oh, ol;
#pragma unroll
    for (int j = 0; j < 4; ++j) {
      const float f = tile[hrow][c4 + j];
      const u16 hv = f2bf(f);
      oh[j] = hv;
      ol[j] = f2bf(f - bf2f(hv));
    }
    *(u16x4*)(hi_o + (size_t)(bh + hrow) * 1024 + bj + c4) = oh;
    *(u16x4*)(lo_o + (size_t)(bh + hrow) * 1024 + bj + c4) = ol;
  }
}

// ---------------- 8-phase split-precision 3-pass GEMM, conflict-free LDS ----------------
// C = (Ah+Al) @ (Bh+Bl)^T, acc = AhBh + AhBl + AlBh.  K=1024, lda=ldb=1024.
// 256x256 tile, BK=32, 8 waves (2x4), wave tile 128x64, 4 phases/K-tile.
// LDS 128 KiB: dbuf x {Apair,Bpair} x [256 rows][8 chunks of 8 u16] (128-B pitch).
// Row r chunk c holds GLOBAL chunk g = c^(r&7); g<4: hi k-chunk g, g>=4: lo k-chunk g-4.
// Frag reads: hi at c = fk^(r&7), lo at c^4 -> 8 bank-quads, 2-way only (free).
// Inverse permutation folded into per-lane global source (gload_lds dest linear).
// CMODE 0: qp (M=16384, split bf16 out). CMODE 1: scores (B=32 batches, f32 out).
template <int CMODE>
__global__ __launch_bounds__(512) void gemm3_8ph_k(
    const u16* __restrict__ Ah_, const u16* __restrict__ Al_,
    const u16* __restrict__ Bh_, const u16* __restrict__ Bl_,
    void* __restrict__ C0, void* __restrict__ C1) {
  __shared__ u16 lds[2][2][256 * 64];  // 131072 B
  const int bid = blockIdx.x;
  const int swz = (bid & 7) * 32 + (bid >> 3);  // bijective on 256; XCD-chunked
  int m0, n0;
  const u16 *Ah, *Al, *Bh, *Bl;
  float* Cf = nullptr;
  u16 *Chi = nullptr, *Clo = nullptr;
  if (CMODE == 0) {
    m0 = (swz >> 2) * 256;
    n0 = (swz & 3) * 256;
    Ah = Ah_; Al = Al_; Bh = Bh_; Bl = Bl_;
    Chi = (u16*)C0; Clo = (u16*)C1;
  } else {
    const int z = swz >> 3;               // 4 consecutive batches per XCD
    m0 = ((swz >> 2) & 1) * 256;
    n0 = (swz & 3) * 256;
    Ah = Ah_ + (size_t)z * 512 * 1024;  Al = Al_ + (size_t)z * 512 * 1024;
    Bh = Bh_ + (size_t)z * 1024 * 1024; Bl = Bl_ + (size_t)z * 1024 * 1024;
    Cf = (float*)C0 + (size_t)z * 512 * 1024;
  }
  const int tid = threadIdx.x;
  const int lane = tid & 63, wid = tid >> 6;
  const int wr = wid >> 2, wc = wid & 3;     // 2 x 4 waves
  const int fr = lane & 15, fk = lane >> 4;  // frag row, k-chunk (0..3)

  f32x4 acc[8][4] = {};

  // stage one hi/lo pair's K-tile: 2048 slots of 16B, 4 per thread
#define STAGE3(pb, q, gph, gpl, rb, kt)                                        \
  {                                                                            \
    _Pragma("unroll") for (int j = 0; j < 4; ++j) {                            \
      const int slot = j * 512 + tid;                                          \
      const int r = slot >> 3;                                                 \
      const int g = (slot & 7) ^ (r & 7);                                      \
      const u16* src = (g < 4) ? (gph) : (gpl);                                \
      gload16(src + (size_t)((rb) + r) * 1024 + (kt) * 32 + (g & 3) * 8,       \
              &lds[pb][q][(j * 512 + wid * 64) * 8]);                          \
    }                                                                          \
  }

  // prologue: tile 0 into buf 0
  STAGE3(0, 0, Ah, Al, m0, 0);
  STAGE3(0, 1, Bh, Bl, n0, 0);

  for (int t = 0; t < 32; ++t) {
    const int p = t & 1;
    WAIT_VM0();
    BAR();
    short8 bh[4], bl[4];
#pragma unroll
    for (int ph = 0; ph < 4; ++ph) {
      short8 ah[2], al[2];
#pragma unroll
      for (int i = 0; i < 2; ++i) {
        const int r = wr * 128 + (ph * 2 + i) * 16 + fr;
        const int ch = fk ^ (r & 7);
        ah[i] = *(const short8*)&lds[p][0][r * 64 + ch * 8];
        al[i] = *(const short8*)&lds[p][0][r * 64 + (ch ^ 4) * 8];
      }
      if (ph == 0) {
#pragma unroll
        for (int nf = 0; nf < 4; ++nf) {
          const int rn = wc * 64 + nf * 16 + fr;
          const int cn = fk ^ (rn & 7);
          bh[nf] = *(const short8*)&lds[p][1][rn * 64 + cn * 8];
          bl[nf] = *(const short8*)&lds[p][1][rn * 64 + (cn ^ 4) * 8];
        }
        if (t < 31) STAGE3(p ^ 1, 0, Ah, Al, m0, t + 1);
      }
      if (ph == 1 && t < 31) STAGE3(p ^ 1, 1, Bh, Bl, n0, t + 1);
      BAR();
      WAIT_LGKM0();
      __builtin_amdgcn_sched_barrier(0);
      __builtin_amdgcn_s_setprio(1);
#pragma unroll
      for (int i = 0; i < 2; ++i)
#pragma unroll
        for (int nf = 0; nf < 4; ++nf) {
          acc[ph * 2 + i][nf] =
              __builtin_amdgcn_mfma_f32_16x16x32_bf16(ah[i], bh[nf], acc[ph * 2 + i][nf], 0, 0, 0);
          acc[ph * 2 + i][nf] =
              __builtin_amdgcn_mfma_f32_16x16x32_bf16(ah[i], bl[nf], acc[ph * 2 + i][nf], 0, 0, 0);
          acc[ph * 2 + i][nf] =
              __builtin_amdgcn_mfma_f32_16x16x32_bf16(al[i], bh[nf], acc[ph * 2 + i][nf], 0, 0, 0);
        }
      __builtin_amdgcn_s_setprio(0);
      BAR();
    }
  }
#undef STAGE3

  const int cb = n0 + wc * 64 + fr;
  const int rb = m0 + wr * 128 + fk * 4;
  if (CMODE == 0) {
#pragma unroll
    for (int mf = 0; mf < 8; ++mf)
#pragma unroll
      for (int nf = 0; nf < 4; ++nf) {
        const int col = cb + nf * 16;
#pragma unroll
        for (int j = 0; j < 4; ++j) {
          const int row = rb + mf * 16 + j;
          const float kv = acc[mf][nf][j];
          const u16 hi = f2bf(kv);
          Chi[(size_t)row * 1024 + col] = hi;
          Clo[(size_t)row * 1024 + col] = f2bf(kv - bf2f(hi));
        }
      }
  } else {
#pragma unroll
    for (int mf = 0; mf < 8; ++mf)
#pragma unroll
      for (int nf = 0; nf < 4; ++nf) {
        const int col = cb + nf * 16;
#pragma unroll
        for (int j = 0; j < 4; ++j) {
          const int row = rb + mf * 16 + j;
          Cf[(size_t)row * 1024 + col] = acc[mf][nf][j];
        }
      }
  }
}

// ---------------- single-pass 8-phase GEMM: C = A @ Bt^T ----------------
// CM 0: ctx = attn[b] @ hT[b]^T, batched, bf16 out.
// CM 1: out = sigmoid(A @ Bt^T + bias), flat M=16384, f32 out.
template <int CM>
__global__ __launch_bounds__(512) void gemm1_8ph_k(
    const u16* __restrict__ A_, const u16* __restrict__ Bt_,
    const float* __restrict__ bias, void* __restrict__ Cout) {
  __shared__ u16 lds[2][2][256 * 64];  // 131072 B
  const int bid = blockIdx.x;
  const int swz = (bid & 7) * 32 + (bid >> 3);
  int m0, n0;
  const u16 *A, *Bt;
  float* Cf = nullptr;
  u16* Cb = nullptr;
  if (CM == 0) {
    const int z = swz >> 3;
    m0 = ((swz >> 2) & 1) * 256;
    n0 = (swz & 3) * 256;
    A = A_ + (size_t)z * 512 * 1024;
    Bt = Bt_ + (size_t)z * 1024 * 1024;
    Cb = (u16*)Cout + (size_t)z * 512 * 1024;
  } else {
    m0 = (swz >> 2) * 256;
    n0 = (swz & 3) * 256;
    A = A_; Bt = Bt_;
    Cf = (float*)Cout;
  }
  const int tid = threadIdx.x;
  const int lane = tid & 63, wid = tid >> 6;
  const int wr = wid >> 2, wc = wid & 3;
  const int fr = lane & 15, fk = lane >> 4;

  f32x4 acc[8][4] = {};

#define STAGE1(pb, q, gp, rb, kt)                                              \
  {                                                                            \
    _Pragma("unroll") for (int j = 0; j < 4; ++j) {                            \
      const int slot = j * 512 + tid;                                          \
      const int r = slot >> 3;                                                 \
      const int g = (slot & 7) ^ (r & 7);                                      \
      gload16((gp) + (size_t)((rb) + r) * 1024 + (kt) * 64 + g * 8,            \
              &lds[pb][q][(j * 512 + wid * 64) * 8]);                          \
    }                                                                          \
  }

  STAGE1(0, 0, A, m0, 0);
  STAGE1(0, 1, Bt, n0, 0);

  for (int t = 0; t < 16; ++t) {
    const int p = t & 1;
    WAIT_VM0();
    BAR();
    short8 bfr[4][2];
#pragma unroll
    for (int ph = 0; ph < 4; ++ph) {
      short8 a[2][2];
#pragma unroll
      for (int i = 0; i < 2; ++i) {
        const int r = wr * 128 + (ph * 2 + i) * 16 + fr;
#pragma unroll
        for (int ks = 0; ks < 2; ++ks) {
          const int g = (ks * 4 + fk) ^ (r & 7);
          a[i][ks] = *(const short8*)&lds[p][0][r * 64 + g * 8];
        }
      }
      if (ph == 0) {
#pragma unroll
        for (int nf = 0; nf < 4; ++nf) {
          const int rn = wc * 64 + nf * 16 + fr;
#pragma unroll
          for (int ks = 0; ks < 2; ++ks) {
            const int g = (ks * 4 + fk) ^ (rn & 7);
            bfr[nf][ks] = *(const short8*)&lds[p][1][rn * 64 + g * 8];
          }
        }
        if (t < 15) {
          STAGE1(p ^ 1, 0, A, m0, t + 1);
          STAGE1(p ^ 1, 1, Bt, n0, t + 1);
        }
      }
      BAR();
      WAIT_LGKM0();
      __builtin_amdgcn_sched_barrier(0);
      __builtin_amdgcn_s_setprio(1);
#pragma unroll
      for (int i = 0; i < 2; ++i)
#pragma unroll
        for (int nf = 0; nf < 4; ++nf) {
          acc[ph * 2 + i][nf] = __builtin_amdgcn_mfma_f32_16x16x32_bf16(
              a[i][0], bfr[nf][0], acc[ph * 2 + i][nf], 0, 0, 0);
          acc[ph * 2 + i][nf] = __builtin_amdgcn_mfma_f32_16x16x32_bf16(
              a[i][1], bfr[nf][1], acc[ph * 2 + i][nf], 0, 0, 0);
        }
      __builtin_amdgcn_s_setprio(0);
      BAR();
    }
  }
#undef STAGE1

  const int cb = n0 + wc * 64 + fr;
  const int rb = m0 + wr * 128 + fk * 4;
  if (CM == 0) {
#pragma unroll
    for (int mf = 0; mf < 8; ++mf)
#pragma unroll
      for (int nf = 0; nf < 4; ++nf) {
        const int col = cb + nf * 16;
#pragma unroll
        for (int j = 0; j < 4; ++j) {
          const int row = rb + mf * 16 + j;
          Cb[(size_t)row * 1024 + col] = f2bf(acc[mf][nf][j]);
        }
      }
  } else {
#pragma unroll
    for (int mf = 0; mf < 8; ++mf)
#pragma unroll
      for (int nf = 0; nf < 4; ++nf) {
        const int col = cb + nf * 16;
        const float bv = bias[col];
#pragma unroll
        for (int j = 0; j < 4; ++j) {
          const int row = rb + mf * 16 + j;
          const float xv = acc[mf][nf][j] + bv;
          Cf[(size_t)row * 1024 + col] = 1.0f / (1.0f + __expf(-xv));
        }
      }
  }
}

// ---------------- softmax over last dim (1024), writes compact bf16 attn ----------------
__global__ __launch_bounds__(256) void softmax_k(const float* __restrict__ S,
                                                 u16* __restrict__ Attn) {
  const float* rp = S + (size_t)blockIdx.x * 1024;
  const int tid = threadIdx.x;
  const int lane = tid & 63, wid = tid >> 6;
  const f32x4 v = ((const f32x4*)rp)[tid];
  float mx = fmaxf(fmaxf(v[0], v[1]), fmaxf(v[2], v[3]));
#pragma unroll
  for (int off = 32; off; off >>= 1) mx = fmaxf(mx, __shfl_xor(mx, off));
  __shared__ float red[4];
  __shared__ float red2[4];
  if (lane == 0) red[wid] = mx;
  __syncthreads();
  mx = fmaxf(fmaxf(red[0], red[1]), fmaxf(red[2], red[3]));
  const float e0 = __expf(v[0] - mx), e1 = __expf(v[1] - mx);
  const float e2 = __expf(v[2] - mx), e3 = __expf(v[3] - mx);
  float s = (e0 + e1) + (e2 + e3);
#pragma unroll
  for (int off = 32; off; off >>= 1) s += __shfl_xor(s, off);
  if (lane == 0) red2[wid] = s;
  __syncthreads();
  const float inv = 1.0f / (red2[0] + red2[1] + red2[2] + red2[3]);
  u16x4 o;
  o[0] = f2bf(e0 * inv); o[1] = f2bf(e1 * inv); o[2] = f2bf(e2 * inv); o[3] = f2bf(e3 * inv);
  ((u16x4*)(Attn + (size_t)blockIdx.x * 1024))[tid] = o;
}

// ---------------- launch ----------------
// Shapes: S=1024, B=32, H=1024, T=512.
//   q'  = x @ K_w                      (split 3-pass, 8-phase; K_b dropped)
//   scr = q'[b] @ hidden[b]^T          (split 3-pass, 8-phase, f32)
//   attn = softmax(scr)                (compact bf16 [B,T,S])
//   ctx = attn[b] @ hT[b]^T            (single-pass 8-phase, bf16)
//   out = sigmoid(ctx @ V_w^T + V_b)   (single-pass 8-phase, f32)
// ws (MB): hhi 0-64 (→ctx 0-32) | hlo 64-128 | hT 128-192 |
//   qhi 192-224, qlo 224-256 (→attn 192-224) | scores f32 256-320 | weights 320-326
extern "C" void kernel_launch(void* const* d_in, const int* in_sizes, int n_in,
                              void* d_out, int out_size, void* d_ws, size_t ws_size,
                              hipStream_t stream) {
  const float* hidden = (const float*)d_in[0];
  const float* x = (const float*)d_in[1];
  // d_in[2] problem_q unused; d_in[4] K_b dropped (softmax shift invariance)
  const float* K_w = (const float*)d_in[3];
  const float* V_w = (const float*)d_in[5];
  const float* V_b = (const float*)d_in[6];

  char* ws = (char*)d_ws;
  u16* hhi = (u16*)(ws);
  u16* hlo = (u16*)(ws + 67108864);
  u16* hT  = (u16*)(ws + 134217728);
  u16* qhi = (u16*)(ws + 201326592);
  u16* qlo = (u16*)(ws + 234881024);
  float* scoresF = (float*)(ws + 268435456);
  u16* attn = qhi;          // reuse (q' dead after scores)
  u16* ctx = hhi;           // reuse (hhi dead after scores)
  u16* kwt_h = (u16*)(ws + 335544320);
  u16* kwt_l = kwt_h + 1024 * 1024;
  u16* vw = kwt_h + 2 * 1024 * 1024;
  u16* xhi = (u16*)d_out;
  u16* xlo = xhi + 32L * 512 * 1024;
  float* out = (float*)d_out;

  // 1. hidden [S,B,H] -> split bf16 [B,S,H] + transposed hi [B,H,S]
  cvt_hidden3_k<<<dim3(16, 16, 32), 256, 0, stream>>>(hidden, hhi, hlo, hT);
  // 2. x -> split bf16 (into d_out; dead before final GEMM overwrites it)
  cvt_split_k<<<2048, 256, 0, stream>>>(x, xhi, xlo, 32L * 512 * 1024 / 4);
  // 3. weights: K_w transposed split, V_w single
  cvt_w_split_t_k<<<dim3(16, 16), 256, 0, stream>>>(K_w, kwt_h, kwt_l);
  cvt_f32_bf16_k<<<1024, 256, 0, stream>>>(V_w, vw, 1024L * 1024 / 4);
  // 4. q' = x @ K_w  (split 3-pass, 8-phase 256^2, conflict-free LDS)
  gemm3_8ph_k<0><<<256, 512, 0, stream>>>(xhi, xlo, kwt_h, kwt_l, qhi, qlo);
  // 5. scores[b] = q'[b] @ hidden[b]^T  (split 3-pass, 8-phase 256^2, f32 out)
  gemm3_8ph_k<1><<<256, 512, 0, stream>>>(qhi, qlo, hhi, hlo, scoresF, nullptr);
  // 6. softmax over S -> compact bf16 attn
  softmax_k<<<16384, 256, 0, stream>>>(scoresF, attn);
  // 7. ctx[b] = attn[b] @ hT[b]^T  (single-pass 8-phase)
  gemm1_8ph_k<0><<<256, 512, 0, stream>>>(attn, hT, nullptr, ctx);
  // 8. out = sigmoid(ctx @ V_w^T + V_b)  (single-pass 8-phase)
  gemm1_8ph_k<1><<<256, 512, 0, stream>>>(ctx, vw, V_b, out);
}

// Round 8
// 349.371 us; speedup vs baseline: 2.1788x; 1.0834x over previous
//
#include <hip/hip_runtime.h>

typedef unsigned short u16;
typedef __attribute__((ext_vector_type(8))) short short8;
typedef __attribute__((ext_vector_type(8))) _Float16 half8;
typedef __attribute__((ext_vector_type(4))) float f32x4;
typedef __attribute__((ext_vector_type(4))) u16 u16x4;
typedef __attribute__((ext_vector_type(4))) unsigned int u32x4;

#define DEVINL static __device__ __forceinline__

DEVINL u16 f2bf(float f) {
  unsigned u = __builtin_bit_cast(unsigned, f);
  u += 0x7fffu + ((u >> 16) & 1u);
  return (u16)(u >> 16);
}
DEVINL float bf2f(u16 h) {
  return __builtin_bit_cast(float, ((unsigned)h) << 16);
}
DEVINL u16 f2h(float f) { return __builtin_bit_cast(u16, (_Float16)f); }
DEVINL float h2f(u16 h) { return (float)__builtin_bit_cast(_Float16, h); }

// async global->LDS, 16B per lane; lds base must be wave-uniform
DEVINL void gload16(const void* g, void* l) {
  __builtin_amdgcn_global_load_lds(
      (const __attribute__((address_space(1))) void*)g,
      (__attribute__((address_space(3))) void*)l, 16, 0, 0);
}

#define BAR() asm volatile("s_barrier" ::: "memory")
#define WAIT_VM0() asm volatile("s_waitcnt vmcnt(0)" ::: "memory")
#define WAIT_LGKM0() asm volatile("s_waitcnt lgkmcnt(0)" ::: "memory")

// ---------------- converts ----------------

// hidden [S=1024,B=32,H=1024] f32 -> hf16 [B,S,H] fp16 + hT [B,H,S] bf16
__global__ __launch_bounds__(256) void cvt_hidden2_k(const float* __restrict__ hid,
                                                     u16* __restrict__ hf,
                                                     u16* __restrict__ hT) {
  __shared__ u16 tl[64][72];
  const int s0 = blockIdx.x * 64;
  const int h0 = blockIdx.y * 64;
  const int b = blockIdx.z;
  const int t = threadIdx.x;
  const int r = t >> 4;
  const int c4 = (t & 15) * 4;
#pragma unroll
  for (int it = 0; it < 4; ++it) {
    const int s = it * 16 + r;
    const f32x4 v = *(const f32x4*)(hid + ((size_t)(s0 + s) * 32 + b) * 1024 + h0 + c4);
    u16x4 of;
#pragma unroll
    for (int j = 0; j < 4; ++j) {
      of[j] = f2h(v[j]);
      tl[s][c4 + j] = f2bf(v[j]);
    }
    *(u16x4*)(hf + ((size_t)b * 1024 + s0 + s) * 1024 + h0 + c4) = of;
  }
  __syncthreads();
  const int h = t >> 2;
  const int sq = (t & 3) * 16;
  u16 tmp[16] __attribute__((aligned(16)));
#pragma unroll
  for (int i = 0; i < 16; ++i) tmp[i] = tl[sq + i][h];
  u16* dst = hT + ((size_t)b * 1024 + h0 + h) * 1024 + s0 + sq;
  *(u32x4*)(dst) = *(const u32x4*)&tmp[0];
  *(u32x4*)(dst + 8) = *(const u32x4*)&tmp[8];
}

// generic f32 -> split bf16 (hi, lo)
__global__ __launch_bounds__(256) void cvt_split_k(const float* __restrict__ in,
                                                   u16* __restrict__ hi_o,
                                                   u16* __restrict__ lo_o, long n4) {
  long i = (long)blockIdx.x * 256 + threadIdx.x;
  const long stride = (long)gridDim.x * 256;
  for (; i < n4; i += stride) {
    const f32x4 v = ((const f32x4*)in)[i];
    u16x4 oh, ol;
#pragma unroll
    for (int j = 0; j < 4; ++j) {
      const u16 hi = f2bf(v[j]);
      oh[j] = hi;
      ol[j] = f2bf(v[j] - bf2f(hi));
    }
    ((u16x4*)hi_o)[i] = oh;
    ((u16x4*)lo_o)[i] = ol;
  }
}

// generic f32 -> bf16 (single)
__global__ __launch_bounds__(256) void cvt_f32_bf16_k(const float* __restrict__ in,
                                                      u16* __restrict__ out, long n4) {
  long i = (long)blockIdx.x * 256 + threadIdx.x;
  const long stride = (long)gridDim.x * 256;
  for (; i < n4; i += stride) {
    const f32x4 v = ((const f32x4*)in)[i];
    u16x4 o;
#pragma unroll
    for (int j = 0; j < 4; ++j) o[j] = f2bf(v[j]);
    ((u16x4*)out)[i] = o;
  }
}

// K_w [j=1024][h=1024] f32 -> transposed split bf16: out[h][j]
__global__ __launch_bounds__(256) void cvt_w_split_t_k(const float* __restrict__ in,
                                                       u16* __restrict__ hi_o,
                                                       u16* __restrict__ lo_o) {
  __shared__ float tile[64][65];
  const int bh = blockIdx.x * 64;
  const int bj = blockIdx.y * 64;
  const int t = threadIdx.x;
  const int r = t >> 4;
  const int c4 = (t & 15) * 4;
#pragma unroll
  for (int it = 0; it < 4; ++it) {
    const int row = it * 16 + r;
    const f32x4 v = *(const f32x4*)(in + (size_t)(bj + row) * 1024 + bh + c4);
#pragma unroll
    for (int j = 0; j < 4; ++j) tile[c4 + j][row] = v[j];
  }
  __syncthreads();
#pragma unroll
  for (int it = 0; it < 4; ++it) {
    const int hrow = it * 16 + r;
    u16x4 oh, ol;
#pragma unroll
    for (int j = 0; j < 4; ++j) {
      const float f = tile[hrow][c4 + j];
      const u16 hv = f2bf(f);
      oh[j] = hv;
      ol[j] = f2bf(f - bf2f(hv));
    }
    *(u16x4*)(hi_o + (size_t)(bh + hrow) * 1024 + bj + c4) = oh;
    *(u16x4*)(lo_o + (size_t)(bh + hrow) * 1024 + bj + c4) = ol;
  }
}

// ---------------- qp: 8-phase split-bf16 3-pass GEMM, fp16-split out ----------------
// q' = (xh+xl) @ (kwh+kwl)^T. M=16384, N=1024, K=1024. 256x256, BK=32, 8 waves.
// LDS pair layout: row r chunk c holds global chunk g=c^(r&7); g<4 hi, g>=4 lo.
__global__ __launch_bounds__(512) void gemm3_8ph_k(
    const u16* __restrict__ Ah, const u16* __restrict__ Al,
    const u16* __restrict__ Bh, const u16* __restrict__ Bl,
    u16* __restrict__ Chi, u16* __restrict__ Clo) {
  __shared__ u16 lds[2][2][256 * 64];  // 131072 B
  const int bid = blockIdx.x;
  const int swz = (bid & 7) * 32 + (bid >> 3);
  const int m0 = (swz >> 2) * 256;
  const int n0 = (swz & 3) * 256;
  const int tid = threadIdx.x;
  const int lane = tid & 63, wid = tid >> 6;
  const int wr = wid >> 2, wc = wid & 3;
  const int fr = lane & 15, fk = lane >> 4;

  f32x4 acc[8][4] = {};

#define STAGE3(pb, q, gph, gpl, rb, kt)                                        \
  {                                                                            \
    _Pragma("unroll") for (int j = 0; j < 4; ++j) {                            \
      const int slot = j * 512 + tid;                                          \
      const int r = slot >> 3;                                                 \
      const int g = (slot & 7) ^ (r & 7);                                      \
      const u16* src = (g < 4) ? (gph) : (gpl);                                \
      gload16(src + (size_t)((rb) + r) * 1024 + (kt) * 32 + (g & 3) * 8,       \
              &lds[pb][q][(j * 512 + wid * 64) * 8]);                          \
    }                                                                          \
  }

  STAGE3(0, 0, Ah, Al, m0, 0);
  STAGE3(0, 1, Bh, Bl, n0, 0);

  for (int t = 0; t < 32; ++t) {
    const int p = t & 1;
    WAIT_VM0();
    BAR();
    short8 bh[4], bl[4];
#pragma unroll
    for (int ph = 0; ph < 4; ++ph) {
      short8 ah[2], al[2];
#pragma unroll
      for (int i = 0; i < 2; ++i) {
        const int r = wr * 128 + (ph * 2 + i) * 16 + fr;
        const int ch = fk ^ (r & 7);
        ah[i] = *(const short8*)&lds[p][0][r * 64 + ch * 8];
        al[i] = *(const short8*)&lds[p][0][r * 64 + (ch ^ 4) * 8];
      }
      if (ph == 0) {
#pragma unroll
        for (int nf = 0; nf < 4; ++nf) {
          const int rn = wc * 64 + nf * 16 + fr;
          const int cn = fk ^ (rn & 7);
          bh[nf] = *(const short8*)&lds[p][1][rn * 64 + cn * 8];
          bl[nf] = *(const short8*)&lds[p][1][rn * 64 + (cn ^ 4) * 8];
        }
        if (t < 31) STAGE3(p ^ 1, 0, Ah, Al, m0, t + 1);
      }
      if (ph == 1 && t < 31) STAGE3(p ^ 1, 1, Bh, Bl, n0, t + 1);
      BAR();
      WAIT_LGKM0();
      __builtin_amdgcn_sched_barrier(0);
      __builtin_amdgcn_s_setprio(1);
#pragma unroll
      for (int i = 0; i < 2; ++i)
#pragma unroll
        for (int nf = 0; nf < 4; ++nf) {
          acc[ph * 2 + i][nf] =
              __builtin_amdgcn_mfma_f32_16x16x32_bf16(ah[i], bh[nf], acc[ph * 2 + i][nf], 0, 0, 0);
          acc[ph * 2 + i][nf] =
              __builtin_amdgcn_mfma_f32_16x16x32_bf16(ah[i], bl[nf], acc[ph * 2 + i][nf], 0, 0, 0);
          acc[ph * 2 + i][nf] =
              __builtin_amdgcn_mfma_f32_16x16x32_bf16(al[i], bh[nf], acc[ph * 2 + i][nf], 0, 0, 0);
        }
      __builtin_amdgcn_s_setprio(0);
      BAR();
    }
  }
#undef STAGE3

  const int cb = n0 + wc * 64 + fr;
  const int rb = m0 + wr * 128 + fk * 4;
#pragma unroll
  for (int mf = 0; mf < 8; ++mf)
#pragma unroll
    for (int nf = 0; nf < 4; ++nf) {
      const int col = cb + nf * 16;
#pragma unroll
      for (int j = 0; j < 4; ++j) {
        const int row = rb + mf * 16 + j;
        const float kv = acc[mf][nf][j];
        const u16 hi = f2h(kv);
        Chi[(size_t)row * 1024 + col] = hi;
        Clo[(size_t)row * 1024 + col] = f2h(kv - h2f(hi));
      }
    }
}

// ---------------- scores: 8-phase 2-pass fp16 GEMM, batched, f32 out ----------------
// scores[b] = (Qh+Ql)[b] @ Hf[b]^T.  A-pair fp16 (128B rows), B single fp16 (64B rows).
// B layout: slot = r*4+c holds global chunk g = c ^ ((r>>1)&3)  (8 banks, 2-way free).
__global__ __launch_bounds__(512) void gemm2_8ph_k(
    const u16* __restrict__ Qh_, const u16* __restrict__ Ql_,
    const u16* __restrict__ Hf_, float* __restrict__ S) {
  __shared__ u16 lA[2][256 * 64];  // 64 KiB
  __shared__ u16 lB[2][256 * 32];  // 32 KiB
  const int bid = blockIdx.x;
  const int swz = (bid & 7) * 32 + (bid >> 3);
  const int z = swz >> 3;
  const int m0 = ((swz >> 2) & 1) * 256;
  const int n0 = (swz & 3) * 256;
  const u16* Qh = Qh_ + (size_t)z * 512 * 1024;
  const u16* Ql = Ql_ + (size_t)z * 512 * 1024;
  const u16* Hf = Hf_ + (size_t)z * 1024 * 1024;
  float* Cf = S + (size_t)z * 512 * 1024;
  const int tid = threadIdx.x;
  const int lane = tid & 63, wid = tid >> 6;
  const int wr = wid >> 2, wc = wid & 3;
  const int fr = lane & 15, fk = lane >> 4;

  f32x4 acc[8][4] = {};

#define STAGEA(pb, kt)                                                         \
  {                                                                            \
    _Pragma("unroll") for (int j = 0; j < 4; ++j) {                            \
      const int slot = j * 512 + tid;                                          \
      const int r = slot >> 3;                                                 \
      const int g = (slot & 7) ^ (r & 7);                                      \
      const u16* src = (g < 4) ? Qh : Ql;                                      \
      gload16(src + (size_t)(m0 + r) * 1024 + (kt) * 32 + (g & 3) * 8,         \
              &lA[pb][(j * 512 + wid * 64) * 8]);                              \
    }                                                                          \
  }
#define STAGEB(pb, kt)                                                         \
  {                                                                            \
    _Pragma("unroll") for (int j = 0; j < 2; ++j) {                            \
      const int slot = j * 512 + tid;                                          \
      const int r = slot >> 2;                                                 \
      const int g = (slot & 3) ^ ((r >> 1) & 3);                               \
      gload16(Hf + (size_t)(n0 + r) * 1024 + (kt) * 32 + g * 8,                \
              &lB[pb][(j * 512 + wid * 64) * 8]);                              \
    }                                                                          \
  }

  STAGEA(0, 0);
  STAGEB(0, 0);

  for (int t = 0; t < 32; ++t) {
    const int p = t & 1;
    WAIT_VM0();
    BAR();
    half8 bf[4];
#pragma unroll
    for (int ph = 0; ph < 4; ++ph) {
      half8 ah[2], al[2];
#pragma unroll
      for (int i = 0; i < 2; ++i) {
        const int r = wr * 128 + (ph * 2 + i) * 16 + fr;
        const int ch = fk ^ (r & 7);
        ah[i] = *(const half8*)&lA[p][r * 64 + ch * 8];
        al[i] = *(const half8*)&lA[p][r * 64 + (ch ^ 4) * 8];
      }
      if (ph == 0) {
#pragma unroll
        for (int nf = 0; nf < 4; ++nf) {
          const int rn = wc * 64 + nf * 16 + fr;
          const int cn = fk ^ ((rn >> 1) & 3);
          bf[nf] = *(const half8*)&lB[p][rn * 32 + cn * 8];
        }
        if (t < 31) STAGEA(p ^ 1, t + 1);
      }
      if (ph == 1 && t < 31) STAGEB(p ^ 1, t + 1);
      BAR();
      WAIT_LGKM0();
      __builtin_amdgcn_sched_barrier(0);
      __builtin_amdgcn_s_setprio(1);
#pragma unroll
      for (int i = 0; i < 2; ++i)
#pragma unroll
        for (int nf = 0; nf < 4; ++nf) {
          acc[ph * 2 + i][nf] =
              __builtin_amdgcn_mfma_f32_16x16x32_f16(ah[i], bf[nf], acc[ph * 2 + i][nf], 0, 0, 0);
          acc[ph * 2 + i][nf] =
              __builtin_amdgcn_mfma_f32_16x16x32_f16(al[i], bf[nf], acc[ph * 2 + i][nf], 0, 0, 0);
        }
      __builtin_amdgcn_s_setprio(0);
      BAR();
    }
  }
#undef STAGEA
#undef STAGEB

  const int cb = n0 + wc * 64 + fr;
  const int rb = m0 + wr * 128 + fk * 4;
#pragma unroll
  for (int mf = 0; mf < 8; ++mf)
#pragma unroll
    for (int nf = 0; nf < 4; ++nf) {
      const int col = cb + nf * 16;
#pragma unroll
      for (int j = 0; j < 4; ++j) {
        const int row = rb + mf * 16 + j;
        Cf[(size_t)row * 1024 + col] = acc[mf][nf][j];
      }
    }
}

// ---------------- single-pass 8-phase bf16 GEMM: C = A @ Bt^T ----------------
// CM 0: ctx = attn[b] @ hT[b]^T, batched, bf16 out.
// CM 1: out = sigmoid(A @ Bt^T + bias), flat M=16384, f32 out.
template <int CM>
__global__ __launch_bounds__(512) void gemm1_8ph_k(
    const u16* __restrict__ A_, const u16* __restrict__ Bt_,
    const float* __restrict__ bias, void* __restrict__ Cout) {
  __shared__ u16 lds[2][2][256 * 64];  // 131072 B
  const int bid = blockIdx.x;
  const int swz = (bid & 7) * 32 + (bid >> 3);
  int m0, n0;
  const u16 *A, *Bt;
  float* Cf = nullptr;
  u16* Cb = nullptr;
  if (CM == 0) {
    const int z = swz >> 3;
    m0 = ((swz >> 2) & 1) * 256;
    n0 = (swz & 3) * 256;
    A = A_ + (size_t)z * 512 * 1024;
    Bt = Bt_ + (size_t)z * 1024 * 1024;
    Cb = (u16*)Cout + (size_t)z * 512 * 1024;
  } else {
    m0 = (swz >> 2) * 256;
    n0 = (swz & 3) * 256;
    A = A_; Bt = Bt_;
    Cf = (float*)Cout;
  }
  const int tid = threadIdx.x;
  const int lane = tid & 63, wid = tid >> 6;
  const int wr = wid >> 2, wc = wid & 3;
  const int fr = lane & 15, fk = lane >> 4;

  f32x4 acc[8][4] = {};

#define STAGE1(pb, q, gp, rb, kt)                                              \
  {                                                                            \
    _Pragma("unroll") for (int j = 0; j < 4; ++j) {                            \
      const int slot = j * 512 + tid;                                          \
      const int r = slot >> 3;                                                 \
      const int g = (slot & 7) ^ (r & 7);                                      \
      gload16((gp) + (size_t)((rb) + r) * 1024 + (kt) * 64 + g * 8,            \
              &lds[pb][q][(j * 512 + wid * 64) * 8]);                          \
    }                                                                          \
  }

  STAGE1(0, 0, A, m0, 0);
  STAGE1(0, 1, Bt, n0, 0);

  for (int t = 0; t < 16; ++t) {
    const int p = t & 1;
    WAIT_VM0();
    BAR();
    short8 bfr[4][2];
#pragma unroll
    for (int ph = 0; ph < 4; ++ph) {
      short8 a[2][2];
#pragma unroll
      for (int i = 0; i < 2; ++i) {
        const int r = wr * 128 + (ph * 2 + i) * 16 + fr;
#pragma unroll
        for (int ks = 0; ks < 2; ++ks) {
          const int g = (ks * 4 + fk) ^ (r & 7);
          a[i][ks] = *(const short8*)&lds[p][0][r * 64 + g * 8];
        }
      }
      if (ph == 0) {
#pragma unroll
        for (int nf = 0; nf < 4; ++nf) {
          const int rn = wc * 64 + nf * 16 + fr;
#pragma unroll
          for (int ks = 0; ks < 2; ++ks) {
            const int g = (ks * 4 + fk) ^ (rn & 7);
            bfr[nf][ks] = *(const short8*)&lds[p][1][rn * 64 + g * 8];
          }
        }
        if (t < 15) {
          STAGE1(p ^ 1, 0, A, m0, t + 1);
          STAGE1(p ^ 1, 1, Bt, n0, t + 1);
        }
      }
      BAR();
      WAIT_LGKM0();
      __builtin_amdgcn_sched_barrier(0);
      __builtin_amdgcn_s_setprio(1);
#pragma unroll
      for (int i = 0; i < 2; ++i)
#pragma unroll
        for (int nf = 0; nf < 4; ++nf) {
          acc[ph * 2 + i][nf] = __builtin_amdgcn_mfma_f32_16x16x32_bf16(
              a[i][0], bfr[nf][0], acc[ph * 2 + i][nf], 0, 0, 0);
          acc[ph * 2 + i][nf] = __builtin_amdgcn_mfma_f32_16x16x32_bf16(
              a[i][1], bfr[nf][1], acc[ph * 2 + i][nf], 0, 0, 0);
        }
      __builtin_amdgcn_s_setprio(0);
      BAR();
    }
  }
#undef STAGE1

  const int cb = n0 + wc * 64 + fr;
  const int rb = m0 + wr * 128 + fk * 4;
  if (CM == 0) {
#pragma unroll
    for (int mf = 0; mf < 8; ++mf)
#pragma unroll
      for (int nf = 0; nf < 4; ++nf) {
        const int col = cb + nf * 16;
#pragma unroll
        for (int j = 0; j < 4; ++j) {
          const int row = rb + mf * 16 + j;
          Cb[(size_t)row * 1024 + col] = f2bf(acc[mf][nf][j]);
        }
      }
  } else {
#pragma unroll
    for (int mf = 0; mf < 8; ++mf)
#pragma unroll
      for (int nf = 0; nf < 4; ++nf) {
        const int col = cb + nf * 16;
        const float bv = bias[col];
#pragma unroll
        for (int j = 0; j < 4; ++j) {
          const int row = rb + mf * 16 + j;
          const float xv = acc[mf][nf][j] + bv;
          Cf[(size_t)row * 1024 + col] = 1.0f / (1.0f + __expf(-xv));
        }
      }
  }
}

// ---------------- softmax over last dim (1024), writes compact bf16 attn ----------------
__global__ __launch_bounds__(256) void softmax_k(const float* __restrict__ S,
                                                 u16* __restrict__ Attn) {
  const float* rp = S + (size_t)blockIdx.x * 1024;
  const int tid = threadIdx.x;
  const int lane = tid & 63, wid = tid >> 6;
  const f32x4 v = ((const f32x4*)rp)[tid];
  float mx = fmaxf(fmaxf(v[0], v[1]), fmaxf(v[2], v[3]));
#pragma unroll
  for (int off = 32; off; off >>= 1) mx = fmaxf(mx, __shfl_xor(mx, off));
  __shared__ float red[4];
  __shared__ float red2[4];
  if (lane == 0) red[wid] = mx;
  __syncthreads();
  mx = fmaxf(fmaxf(red[0], red[1]), fmaxf(red[2], red[3]));
  const float e0 = __expf(v[0] - mx), e1 = __expf(v[1] - mx);
  const float e2 = __expf(v[2] - mx), e3 = __expf(v[3] - mx);
  float s = (e0 + e1) + (e2 + e3);
#pragma unroll
  for (int off = 32; off; off >>= 1) s += __shfl_xor(s, off);
  if (lane == 0) red2[wid] = s;
  __syncthreads();
  const float inv = 1.0f / (red2[0] + red2[1] + red2[2] + red2[3]);
  u16x4 o;
  o[0] = f2bf(e0 * inv); o[1] = f2bf(e1 * inv); o[2] = f2bf(e2 * inv); o[3] = f2bf(e3 * inv);
  ((u16x4*)(Attn + (size_t)blockIdx.x * 1024))[tid] = o;
}

// ---------------- launch ----------------
// Shapes: S=1024, B=32, H=1024, T=512.
//   q'  = x @ K_w            (split-bf16 3-pass 8ph; fp16-split out; K_b dropped)
//   scr = q'[b] @ hf16[b]^T  (fp16 2-pass 8ph, f32 out)
//   attn = softmax(scr)      (compact bf16)
//   ctx = attn[b] @ hT[b]^T  (bf16 8ph)
//   out = sigmoid(ctx @ V_w^T + V_b)
// ws (MB): hf16 0-64 (attn reuses 0-32) | hT 64-128 | qhi 128-160 (ctx reuses) |
//          qlo 160-192 | scores f32 192-256 | weights 256-262
extern "C" void kernel_launch(void* const* d_in, const int* in_sizes, int n_in,
                              void* d_out, int out_size, void* d_ws, size_t ws_size,
                              hipStream_t stream) {
  const float* hidden = (const float*)d_in[0];
  const float* x = (const float*)d_in[1];
  // d_in[2] problem_q unused; d_in[4] K_b dropped (softmax shift invariance)
  const float* K_w = (const float*)d_in[3];
  const float* V_w = (const float*)d_in[5];
  const float* V_b = (const float*)d_in[6];

  char* ws = (char*)d_ws;
  u16* hf16 = (u16*)(ws);
  u16* hT = (u16*)(ws + 67108864);
  u16* qhi = (u16*)(ws + 134217728);
  u16* qlo = (u16*)(ws + 167772160);
  float* scoresF = (float*)(ws + 201326592);
  u16* attn = hf16;  // reuse (hf16 dead after scores)
  u16* ctx = qhi;    // reuse (q' dead after scores)
  u16* kwt_h = (u16*)(ws + 268435456);
  u16* kwt_l = kwt_h + 1024 * 1024;
  u16* vw = kwt_h + 2 * 1024 * 1024;
  u16* xhi = (u16*)d_out;
  u16* xlo = xhi + 32L * 512 * 1024;
  float* out = (float*)d_out;

  // 1. hidden [S,B,H] -> fp16 [B,S,H] + transposed bf16 [B,H,S]
  cvt_hidden2_k<<<dim3(16, 16, 32), 256, 0, stream>>>(hidden, hf16, hT);
  // 2. x -> split bf16 (into d_out; dead before final GEMM overwrites it)
  cvt_split_k<<<2048, 256, 0, stream>>>(x, xhi, xlo, 32L * 512 * 1024 / 4);
  // 3. weights: K_w transposed split bf16, V_w single bf16
  cvt_w_split_t_k<<<dim3(16, 16), 256, 0, stream>>>(K_w, kwt_h, kwt_l);
  cvt_f32_bf16_k<<<1024, 256, 0, stream>>>(V_w, vw, 1024L * 1024 / 4);
  // 4. q' = x @ K_w  (split-bf16 3-pass, fp16-split out)
  gemm3_8ph_k<<<256, 512, 0, stream>>>(xhi, xlo, kwt_h, kwt_l, qhi, qlo);
  // 5. scores[b] = q'[b] @ hf16[b]^T  (fp16 2-pass, f32 out)
  gemm2_8ph_k<<<256, 512, 0, stream>>>(qhi, qlo, hf16, scoresF);
  // 6. softmax over S -> compact bf16 attn
  softmax_k<<<16384, 256, 0, stream>>>(scoresF, attn);
  // 7. ctx[b] = attn[b] @ hT[b]^T
  gemm1_8ph_k<0><<<256, 512, 0, stream>>>(attn, hT, nullptr, ctx);
  // 8. out = sigmoid(ctx @ V_w^T + V_b)
  gemm1_8ph_k<1><<<256, 512, 0, stream>>>(ctx, vw, V_b, out);
}

// Round 9
// 338.192 us; speedup vs baseline: 2.2509x; 1.0331x over previous
//
#include <hip/hip_runtime.h>

typedef unsigned short u16;
typedef __attribute__((ext_vector_type(8))) short short8;
typedef __attribute__((ext_vector_type(8))) _Float16 half8;
typedef __attribute__((ext_vector_type(4))) float f32x4;
typedef __attribute__((ext_vector_type(4))) u16 u16x4;
typedef __attribute__((ext_vector_type(4))) unsigned int u32x4;

#define DEVINL static __device__ __forceinline__

DEVINL u16 f2bf(float f) {
  unsigned u = __builtin_bit_cast(unsigned, f);
  u += 0x7fffu + ((u >> 16) & 1u);
  return (u16)(u >> 16);
}
DEVINL float bf2f(u16 h) {
  return __builtin_bit_cast(float, ((unsigned)h) << 16);
}
DEVINL u16 f2h(float f) { return __builtin_bit_cast(u16, (_Float16)f); }
DEVINL float h2f(u16 h) { return (float)__builtin_bit_cast(_Float16, h); }

// async global->LDS, 16B per lane; lds base must be wave-uniform
DEVINL void gload16(const void* g, void* l) {
  __builtin_amdgcn_global_load_lds(
      (const __attribute__((address_space(1))) void*)g,
      (__attribute__((address_space(3))) void*)l, 16, 0, 0);
}

#define BAR() asm volatile("s_barrier" ::: "memory")
#define WAIT_VM0() asm volatile("s_waitcnt vmcnt(0)" ::: "memory")
#define WAIT_LGKM0() asm volatile("s_waitcnt lgkmcnt(0)" ::: "memory")

// ---------------- converts ----------------

// hidden [S=1024,B=32,H=1024] f32 -> hf16 [B,S,H] fp16 + hT [B,H,S] bf16
// LDS transpose with XOR col-swizzle (col ^= ((s>>4)&3)<<2): read conflicts 8-way -> 2-way.
__global__ __launch_bounds__(256) void cvt_hidden2_k(const float* __restrict__ hid,
                                                     u16* __restrict__ hf,
                                                     u16* __restrict__ hT) {
  __shared__ u16 tl[64][72];
  const int s0 = blockIdx.x * 64;
  const int h0 = blockIdx.y * 64;
  const int b = blockIdx.z;
  const int t = threadIdx.x;
  const int r = t >> 4;
  const int c4 = (t & 15) * 4;
#pragma unroll
  for (int it = 0; it < 4; ++it) {
    const int s = it * 16 + r;
    const f32x4 v = *(const f32x4*)(hid + ((size_t)(s0 + s) * 32 + b) * 1024 + h0 + c4);
    u16x4 of;
    const int cs = c4 ^ (it << 2);  // (s>>4)==it here
#pragma unroll
    for (int j = 0; j < 4; ++j) {
      of[j] = f2h(v[j]);
      tl[s][cs + j] = f2bf(v[j]);
    }
    *(u16x4*)(hf + ((size_t)b * 1024 + s0 + s) * 1024 + h0 + c4) = of;
  }
  __syncthreads();
  const int h = t >> 2;
  const int sq = (t & 3) * 16;
  u16 tmp[16] __attribute__((aligned(16)));
#pragma unroll
  for (int i = 0; i < 16; ++i)
    tmp[i] = tl[sq + i][h ^ ((((sq + i) >> 4) & 3) << 2)];
  u16* dst = hT + ((size_t)b * 1024 + h0 + h) * 1024 + s0 + sq;
  *(u32x4*)(dst) = *(const u32x4*)&tmp[0];
  *(u32x4*)(dst + 8) = *(const u32x4*)&tmp[8];
}

// f32 -> split fp16 (hi, lo)
__global__ __launch_bounds__(256) void cvt_split_h_k(const float* __restrict__ in,
                                                     u16* __restrict__ hi_o,
                                                     u16* __restrict__ lo_o, long n4) {
  long i = (long)blockIdx.x * 256 + threadIdx.x;
  const long stride = (long)gridDim.x * 256;
  for (; i < n4; i += stride) {
    const f32x4 v = ((const f32x4*)in)[i];
    u16x4 oh, ol;
#pragma unroll
    for (int j = 0; j < 4; ++j) {
      const u16 hi = f2h(v[j]);
      oh[j] = hi;
      ol[j] = f2h(v[j] - h2f(hi));
    }
    ((u16x4*)hi_o)[i] = oh;
    ((u16x4*)lo_o)[i] = ol;
  }
}

// generic f32 -> bf16 (single)
__global__ __launch_bounds__(256) void cvt_f32_bf16_k(const float* __restrict__ in,
                                                      u16* __restrict__ out, long n4) {
  long i = (long)blockIdx.x * 256 + threadIdx.x;
  const long stride = (long)gridDim.x * 256;
  for (; i < n4; i += stride) {
    const f32x4 v = ((const f32x4*)in)[i];
    u16x4 o;
#pragma unroll
    for (int j = 0; j < 4; ++j) o[j] = f2bf(v[j]);
    ((u16x4*)out)[i] = o;
  }
}

// K_w [j=1024][h=1024] f32 -> transposed single fp16: out[h][j]
__global__ __launch_bounds__(256) void cvt_w_t_h_k(const float* __restrict__ in,
                                                   u16* __restrict__ out) {
  __shared__ float tile[64][65];
  const int bh = blockIdx.x * 64;
  const int bj = blockIdx.y * 64;
  const int t = threadIdx.x;
  const int r = t >> 4;
  const int c4 = (t & 15) * 4;
#pragma unroll
  for (int it = 0; it < 4; ++it) {
    const int row = it * 16 + r;
    const f32x4 v = *(const f32x4*)(in + (size_t)(bj + row) * 1024 + bh + c4);
#pragma unroll
    for (int j = 0; j < 4; ++j) tile[c4 + j][row] = v[j];
  }
  __syncthreads();
#pragma unroll
  for (int it = 0; it < 4; ++it) {
    const int hrow = it * 16 + r;
    u16x4 of;
#pragma unroll
    for (int j = 0; j < 4; ++j) of[j] = f2h(tile[hrow][c4 + j]);
    *(u16x4*)(out + (size_t)(bh + hrow) * 1024 + bj + c4) = of;
  }
}

// ---------------- 8-phase 2-pass fp16 GEMM: C = (Ah+Al) @ B^T ----------------
// A split fp16 (LDS pair rows 128B, chunk g=c^(r&7): g<4 hi, g>=4 lo),
// B single fp16 (LDS rows 64B, chunk g = c ^ ((r>>1)&3)).
// 256x256 tile, BK=32, 8 waves (2x4), wave tile 128x64, 4 phases/K-tile, 96KB LDS.
// CM 0: qp = x @ kwT^T, flat M=16384, fp16-split out (C0 hi, C1 lo).
// CM 1: scores[b] = q'[b] @ hf[b]^T, batched B=32, f32 out (C0).
template <int CM>
__global__ __launch_bounds__(512) void gemm2_8ph_k(
    const u16* __restrict__ Ah_, const u16* __restrict__ Al_,
    const u16* __restrict__ B_, void* __restrict__ C0, void* __restrict__ C1) {
  __shared__ u16 lA[2][256 * 64];  // 64 KiB
  __shared__ u16 lB[2][256 * 32];  // 32 KiB
  const int bid = blockIdx.x;
  const int swz = (bid & 7) * 32 + (bid >> 3);
  int m0, n0;
  const u16 *Ah, *Al, *Bm;
  float* Cf = nullptr;
  u16 *Chi = nullptr, *Clo = nullptr;
  if (CM == 0) {
    m0 = (swz >> 2) * 256;
    n0 = (swz & 3) * 256;
    Ah = Ah_; Al = Al_; Bm = B_;
    Chi = (u16*)C0; Clo = (u16*)C1;
  } else {
    const int z = swz >> 3;
    m0 = ((swz >> 2) & 1) * 256;
    n0 = (swz & 3) * 256;
    Ah = Ah_ + (size_t)z * 512 * 1024;
    Al = Al_ + (size_t)z * 512 * 1024;
    Bm = B_ + (size_t)z * 1024 * 1024;
    Cf = (float*)C0 + (size_t)z * 512 * 1024;
  }
  const int tid = threadIdx.x;
  const int lane = tid & 63, wid = tid >> 6;
  const int wr = wid >> 2, wc = wid & 3;
  const int fr = lane & 15, fk = lane >> 4;

  f32x4 acc[8][4] = {};

#define STAGEA(pb, kt)                                                         \
  {                                                                            \
    _Pragma("unroll") for (int j = 0; j < 4; ++j) {                            \
      const int slot = j * 512 + tid;                                          \
      const int r = slot >> 3;                                                 \
      const int g = (slot & 7) ^ (r & 7);                                      \
      const u16* src = (g < 4) ? Ah : Al;                                      \
      gload16(src + (size_t)(m0 + r) * 1024 + (kt) * 32 + (g & 3) * 8,         \
              &lA[pb][(j * 512 + wid * 64) * 8]);                              \
    }                                                                          \
  }
#define STAGEB(pb, kt)                                                         \
  {                                                                            \
    _Pragma("unroll") for (int j = 0; j < 2; ++j) {                            \
      const int slot = j * 512 + tid;                                          \
      const int r = slot >> 2;                                                 \
      const int g = (slot & 3) ^ ((r >> 1) & 3);                               \
      gload16(Bm + (size_t)(n0 + r) * 1024 + (kt) * 32 + g * 8,                \
              &lB[pb][(j * 512 + wid * 64) * 8]);                              \
    }                                                                          \
  }

  STAGEA(0, 0);
  STAGEB(0, 0);

  for (int t = 0; t < 32; ++t) {
    const int p = t & 1;
    WAIT_VM0();
    BAR();
    half8 bf[4];
#pragma unroll
    for (int ph = 0; ph < 4; ++ph) {
      half8 ah[2], al[2];
#pragma unroll
      for (int i = 0; i < 2; ++i) {
        const int r = wr * 128 + (ph * 2 + i) * 16 + fr;
        const int ch = fk ^ (r & 7);
        ah[i] = *(const half8*)&lA[p][r * 64 + ch * 8];
        al[i] = *(const half8*)&lA[p][r * 64 + (ch ^ 4) * 8];
      }
      if (ph == 0) {
#pragma unroll
        for (int nf = 0; nf < 4; ++nf) {
          const int rn = wc * 64 + nf * 16 + fr;
          const int cn = fk ^ ((rn >> 1) & 3);
          bf[nf] = *(const half8*)&lB[p][rn * 32 + cn * 8];
        }
        if (t < 31) STAGEA(p ^ 1, t + 1);
      }
      if (ph == 1 && t < 31) STAGEB(p ^ 1, t + 1);
      BAR();
      WAIT_LGKM0();
      __builtin_amdgcn_sched_barrier(0);
      __builtin_amdgcn_s_setprio(1);
#pragma unroll
      for (int i = 0; i < 2; ++i)
#pragma unroll
        for (int nf = 0; nf < 4; ++nf) {
          acc[ph * 2 + i][nf] =
              __builtin_amdgcn_mfma_f32_16x16x32_f16(ah[i], bf[nf], acc[ph * 2 + i][nf], 0, 0, 0);
          acc[ph * 2 + i][nf] =
              __builtin_amdgcn_mfma_f32_16x16x32_f16(al[i], bf[nf], acc[ph * 2 + i][nf], 0, 0, 0);
        }
      __builtin_amdgcn_s_setprio(0);
      BAR();
    }
  }
#undef STAGEA
#undef STAGEB

  const int cb = n0 + wc * 64 + fr;
  const int rb = m0 + wr * 128 + fk * 4;
  if (CM == 0) {
#pragma unroll
    for (int mf = 0; mf < 8; ++mf)
#pragma unroll
      for (int nf = 0; nf < 4; ++nf) {
        const int col = cb + nf * 16;
#pragma unroll
        for (int j = 0; j < 4; ++j) {
          const int row = rb + mf * 16 + j;
          const float kv = acc[mf][nf][j];
          const u16 hi = f2h(kv);
          Chi[(size_t)row * 1024 + col] = hi;
          Clo[(size_t)row * 1024 + col] = f2h(kv - h2f(hi));
        }
      }
  } else {
#pragma unroll
    for (int mf = 0; mf < 8; ++mf)
#pragma unroll
      for (int nf = 0; nf < 4; ++nf) {
        const int col = cb + nf * 16;
#pragma unroll
        for (int j = 0; j < 4; ++j) {
          const int row = rb + mf * 16 + j;
          Cf[(size_t)row * 1024 + col] = acc[mf][nf][j];
        }
      }
  }
}

// ---------------- single-pass 8-phase bf16 GEMM: C = A @ Bt^T ----------------
// CM 0: ctx = attn[b] @ hT[b]^T, batched, bf16 out.
// CM 1: out = sigmoid(A @ Bt^T + bias), flat M=16384, f32 out.
template <int CM>
__global__ __launch_bounds__(512) void gemm1_8ph_k(
    const u16* __restrict__ A_, const u16* __restrict__ Bt_,
    const float* __restrict__ bias, void* __restrict__ Cout) {
  __shared__ u16 lds[2][2][256 * 64];  // 131072 B
  const int bid = blockIdx.x;
  const int swz = (bid & 7) * 32 + (bid >> 3);
  int m0, n0;
  const u16 *A, *Bt;
  float* Cf = nullptr;
  u16* Cb = nullptr;
  if (CM == 0) {
    const int z = swz >> 3;
    m0 = ((swz >> 2) & 1) * 256;
    n0 = (swz & 3) * 256;
    A = A_ + (size_t)z * 512 * 1024;
    Bt = Bt_ + (size_t)z * 1024 * 1024;
    Cb = (u16*)Cout + (size_t)z * 512 * 1024;
  } else {
    m0 = (swz >> 2) * 256;
    n0 = (swz & 3) * 256;
    A = A_; Bt = Bt_;
    Cf = (float*)Cout;
  }
  const int tid = threadIdx.x;
  const int lane = tid & 63, wid = tid >> 6;
  const int wr = wid >> 2, wc = wid & 3;
  const int fr = lane & 15, fk = lane >> 4;

  f32x4 acc[8][4] = {};

#define STAGE1(pb, q, gp, rb, kt)                                              \
  {                                                                            \
    _Pragma("unroll") for (int j = 0; j < 4; ++j) {                            \
      const int slot = j * 512 + tid;                                          \
      const int r = slot >> 3;                                                 \
      const int g = (slot & 7) ^ (r & 7);                                      \
      gload16((gp) + (size_t)((rb) + r) * 1024 + (kt) * 64 + g * 8,            \
              &lds[pb][q][(j * 512 + wid * 64) * 8]);                          \
    }                                                                          \
  }

  STAGE1(0, 0, A, m0, 0);
  STAGE1(0, 1, Bt, n0, 0);

  for (int t = 0; t < 16; ++t) {
    const int p = t & 1;
    WAIT_VM0();
    BAR();
    short8 bfr[4][2];
#pragma unroll
    for (int ph = 0; ph < 4; ++ph) {
      short8 a[2][2];
#pragma unroll
      for (int i = 0; i < 2; ++i) {
        const int r = wr * 128 + (ph * 2 + i) * 16 + fr;
#pragma unroll
        for (int ks = 0; ks < 2; ++ks) {
          const int g = (ks * 4 + fk) ^ (r & 7);
          a[i][ks] = *(const short8*)&lds[p][0][r * 64 + g * 8];
        }
      }
      if (ph == 0) {
#pragma unroll
        for (int nf = 0; nf < 4; ++nf) {
          const int rn = wc * 64 + nf * 16 + fr;
#pragma unroll
          for (int ks = 0; ks < 2; ++ks) {
            const int g = (ks * 4 + fk) ^ (rn & 7);
            bfr[nf][ks] = *(const short8*)&lds[p][1][rn * 64 + g * 8];
          }
        }
        if (t < 15) {
          STAGE1(p ^ 1, 0, A, m0, t + 1);
          STAGE1(p ^ 1, 1, Bt, n0, t + 1);
        }
      }
      BAR();
      WAIT_LGKM0();
      __builtin_amdgcn_sched_barrier(0);
      __builtin_amdgcn_s_setprio(1);
#pragma unroll
      for (int i = 0; i < 2; ++i)
#pragma unroll
        for (int nf = 0; nf < 4; ++nf) {
          acc[ph * 2 + i][nf] = __builtin_amdgcn_mfma_f32_16x16x32_bf16(
              a[i][0], bfr[nf][0], acc[ph * 2 + i][nf], 0, 0, 0);
          acc[ph * 2 + i][nf] = __builtin_amdgcn_mfma_f32_16x16x32_bf16(
              a[i][1], bfr[nf][1], acc[ph * 2 + i][nf], 0, 0, 0);
        }
      __builtin_amdgcn_s_setprio(0);
      BAR();
    }
  }
#undef STAGE1

  const int cb = n0 + wc * 64 + fr;
  const int rb = m0 + wr * 128 + fk * 4;
  if (CM == 0) {
#pragma unroll
    for (int mf = 0; mf < 8; ++mf)
#pragma unroll
      for (int nf = 0; nf < 4; ++nf) {
        const int col = cb + nf * 16;
#pragma unroll
        for (int j = 0; j < 4; ++j) {
          const int row = rb + mf * 16 + j;
          Cb[(size_t)row * 1024 + col] = f2bf(acc[mf][nf][j]);
        }
      }
  } else {
#pragma unroll
    for (int mf = 0; mf < 8; ++mf)
#pragma unroll
      for (int nf = 0; nf < 4; ++nf) {
        const int col = cb + nf * 16;
        const float bv = bias[col];
#pragma unroll
        for (int j = 0; j < 4; ++j) {
          const int row = rb + mf * 16 + j;
          const float xv = acc[mf][nf][j] + bv;
          Cf[(size_t)row * 1024 + col] = 1.0f / (1.0f + __expf(-xv));
        }
      }
  }
}

// ---------------- softmax over last dim (1024), writes compact bf16 attn ----------------
__global__ __launch_bounds__(256) void softmax_k(const float* __restrict__ S,
                                                 u16* __restrict__ Attn) {
  const float* rp = S + (size_t)blockIdx.x * 1024;
  const int tid = threadIdx.x;
  const int lane = tid & 63, wid = tid >> 6;
  const f32x4 v = ((const f32x4*)rp)[tid];
  float mx = fmaxf(fmaxf(v[0], v[1]), fmaxf(v[2], v[3]));
#pragma unroll
  for (int off = 32; off; off >>= 1) mx = fmaxf(mx, __shfl_xor(mx, off));
  __shared__ float red[4];
  __shared__ float red2[4];
  if (lane == 0) red[wid] = mx;
  __syncthreads();
  mx = fmaxf(fmaxf(red[0], red[1]), fmaxf(red[2], red[3]));
  const float e0 = __expf(v[0] - mx), e1 = __expf(v[1] - mx);
  const float e2 = __expf(v[2] - mx), e3 = __expf(v[3] - mx);
  float s = (e0 + e1) + (e2 + e3);
#pragma unroll
  for (int off = 32; off; off >>= 1) s += __shfl_xor(s, off);
  if (lane == 0) red2[wid] = s;
  __syncthreads();
  const float inv = 1.0f / (red2[0] + red2[1] + red2[2] + red2[3]);
  u16x4 o;
  o[0] = f2bf(e0 * inv); o[1] = f2bf(e1 * inv); o[2] = f2bf(e2 * inv); o[3] = f2bf(e3 * inv);
  ((u16x4*)(Attn + (size_t)blockIdx.x * 1024))[tid] = o;
}

// ---------------- launch ----------------
// Shapes: S=1024, B=32, H=1024, T=512.
//   q'  = x @ K_w            (fp16 2-pass 8ph: x fp16-split, K_w fp16; fp16-split out)
//   scr = q'[b] @ hf16[b]^T  (fp16 2-pass 8ph, f32 out)
//   attn = softmax(scr)      (compact bf16)
//   ctx = attn[b] @ hT[b]^T  (bf16 8ph)
//   out = sigmoid(ctx @ V_w^T + V_b)
// ws (MB): hf16 0-64 (attn reuses 0-32) | hT 64-128 | qhi 128-160 (ctx reuses) |
//          qlo 160-192 | scores f32 192-256 | weights 256-260
extern "C" void kernel_launch(void* const* d_in, const int* in_sizes, int n_in,
                              void* d_out, int out_size, void* d_ws, size_t ws_size,
                              hipStream_t stream) {
  const float* hidden = (const float*)d_in[0];
  const float* x = (const float*)d_in[1];
  // d_in[2] problem_q unused; d_in[4] K_b dropped (softmax shift invariance)
  const float* K_w = (const float*)d_in[3];
  const float* V_w = (const float*)d_in[5];
  const float* V_b = (const float*)d_in[6];

  char* ws = (char*)d_ws;
  u16* hf16 = (u16*)(ws);
  u16* hT = (u16*)(ws + 67108864);
  u16* qhi = (u16*)(ws + 134217728);
  u16* qlo = (u16*)(ws + 167772160);
  float* scoresF = (float*)(ws + 201326592);
  u16* attn = hf16;  // reuse (hf16 dead after scores)
  u16* ctx = qhi;    // reuse (q' dead after scores)
  u16* kwT = (u16*)(ws + 268435456);
  u16* vw = kwT + 1024 * 1024;
  u16* xhi = (u16*)d_out;
  u16* xlo = xhi + 32L * 512 * 1024;
  float* out = (float*)d_out;

  // 1. hidden [S,B,H] -> fp16 [B,S,H] + transposed bf16 [B,H,S]
  cvt_hidden2_k<<<dim3(16, 16, 32), 256, 0, stream>>>(hidden, hf16, hT);
  // 2. x -> split fp16 (into d_out; dead before final GEMM overwrites it)
  cvt_split_h_k<<<2048, 256, 0, stream>>>(x, xhi, xlo, 32L * 512 * 1024 / 4);
  // 3. weights: K_w transposed fp16, V_w bf16
  cvt_w_t_h_k<<<dim3(16, 16), 256, 0, stream>>>(K_w, kwT);
  cvt_f32_bf16_k<<<1024, 256, 0, stream>>>(V_w, vw, 1024L * 1024 / 4);
  // 4. q' = x @ K_w  (fp16 2-pass, fp16-split out)
  gemm2_8ph_k<0><<<256, 512, 0, stream>>>(xhi, xlo, kwT, qhi, qlo);
  // 5. scores[b] = q'[b] @ hf16[b]^T  (fp16 2-pass, f32 out)
  gemm2_8ph_k<1><<<256, 512, 0, stream>>>(qhi, qlo, hf16, scoresF, nullptr);
  // 6. softmax over S -> compact bf16 attn
  softmax_k<<<16384, 256, 0, stream>>>(scoresF, attn);
  // 7. ctx[b] = attn[b] @ hT[b]^T
  gemm1_8ph_k<0><<<256, 512, 0, stream>>>(attn, hT, nullptr, ctx);
  // 8. out = sigmoid(ctx @ V_w^T + V_b)
  gemm1_8ph_k<1><<<256, 512, 0, stream>>>(ctx, vw, V_b, out);
}